// Round 9
// baseline (583.936 us; speedup 1.0000x reference)
//
#include <hip/hip_runtime.h>
#include <hip/hip_bf16.h>

#define HID 256
#define LN_EPS 1e-5f
#define DENOM_EPS 1e-8f

typedef __attribute__((ext_vector_type(8))) short short8;
typedef __attribute__((ext_vector_type(4))) float f32x4;

#define WP1_ELEMS (28 * 256 * 32)   // K=896 packed, pre-scaled by 0.5
#define WP2_ELEMS (24 * 256 * 32)   // K=768 (3 rels x 256)

__device__ inline unsigned bfpk(float x, float y) {
    __hip_bfloat162 h = __float22bfloat162_rn(make_float2(x, y));
    return *reinterpret_cast<unsigned*>(&h);
}

// Pack weights into fragment-native layout: wp[ks][col][kk] = W[ks*32+kk][col] (*0.5 for wp1)
__global__ __launch_bounds__(256) void kpack(
    const float* __restrict__ wt, const float* __restrict__ wi,
    const float* __restrict__ wrel,
    __hip_bfloat16* __restrict__ wp1, __hip_bfloat16* __restrict__ wp2)
{
    int idx = blockIdx.x * 256 + threadIdx.x;
    if (idx < WP1_ELEMS) {
        int kk = idx & 31, col = (idx >> 5) & 255, ks = idx >> 13;
        int k = ks * 32 + kk;
        float v = (k < 384) ? wt[k * 256 + col] : wi[(k - 384) * 256 + col];
        wp1[idx] = __float2bfloat16(v * 0.5f);
    } else {
        int j = idx - WP1_ELEMS;
        if (j < WP2_ELEMS) {
            int kk = j & 31, col = (j >> 5) & 255, ks = j >> 13;
            int k = ks * 32 + kk;                 // wrel flat [768][256]
            wp2[j] = __float2bfloat16(wrel[k * 256 + col]);
        }
    }
}

// Build per-dst edge chains: next[e] = atomicExch(head[dst], e). head pre-inited to -1.
__global__ __launch_bounds__(256) void kchain(
    const int* __restrict__ edst, int* __restrict__ head, int* __restrict__ nxt, int E)
{
    int e = blockIdx.x * 256 + threadIdx.x;
    if (e < E) nxt[e] = atomicExch(&head[edst[e]], e);
}

// k2: 8 waves/block, wave = one dst node (block = 8 consecutive nodes so each
// 128B line of S_frag is written by one block -> no cross-XCD false sharing).
// Walk chain, acc[rel] += w*h0[src], write S in MFMA-FRAGMENT layout:
// S_frag[rb][ks][g][r][8e] bf16, rb=d>>6, r=d&63, ks=c>>5, g=(c&31)>>3, e=c&7.
// Lane l (c = l*4..l*4+3): ks=rel*8+(l>>3), g=(l&7)>>1, e0=(l&1)*4 -> one uint2 store per rel.
__global__ __launch_bounds__(512) void k2_gather(
    const float* __restrict__ h0, const int* __restrict__ esrc,
    const int* __restrict__ etype, const float* __restrict__ ew,
    const int* __restrict__ head, const int* __restrict__ nxt,
    __hip_bfloat16* __restrict__ Sf, int N)
{
    int w = threadIdx.x >> 6;
    int lane = threadIdx.x & 63;
    int d = blockIdx.x * 8 + w;
    if (d >= N) return;

    f32x4 a0 = {0.f, 0.f, 0.f, 0.f}, a1 = a0, a2 = a0;
    float d0 = 0.f, d1 = 0.f, d2 = 0.f;

    int e = head[d];
    while (e >= 0) {
        int src = esrc[e];
        int ty = etype[e];       // wave-uniform
        float w_ = ew[e];
        const float4 h = *(const float4*)(h0 + (size_t)src * HID + lane * 4);
        f32x4 hw = {w_ * h.x, w_ * h.y, w_ * h.z, w_ * h.w};
        if (ty == 0)      { a0 += hw; d0 += w_; }
        else if (ty == 1) { a1 += hw; d1 += w_; }
        else              { a2 += hw; d2 += w_; }
        e = nxt[e];
    }

    float i0 = 1.0f / fmaxf(d0, DENOM_EPS);
    float i1 = 1.0f / fmaxf(d1, DENOM_EPS);
    float i2 = 1.0f / fmaxf(d2, DENOM_EPS);

    const int rb = d >> 6, r = d & 63;
    const int g = (lane & 7) >> 1;
    const int e0 = (lane & 1) * 4;
    __hip_bfloat16* base = Sf + (size_t)rb * (24 * 256 * 8);
#pragma unroll
    for (int rel = 0; rel < 3; ++rel) {
        const f32x4& a = rel == 0 ? a0 : (rel == 1 ? a1 : a2);
        const float iv = rel == 0 ? i0 : (rel == 1 ? i1 : i2);
        int ks = rel * 8 + (lane >> 3);
        size_t off = ((size_t)ks * 256 + g * 64 + r) * 8 + e0;
        uint2 p = make_uint2(bfpk(a[0] * iv, a[1] * iv), bfpk(a[2] * iv, a[3] * iv));
        *(uint2*)(base + off) = p;
    }
}

// kg0: h0 = ft@wp1a + fi@wp1b (0.5 pre-folded), row 0 zeroed.
// Block 64 rows x 256 cols, 4 waves (wave = 64-col strip), NO LDS, NO BARRIERS:
// each wave loads its A-fragments directly from global f32 (lanes l,l+16,l+32,l+48
// share a row -> 16 rows x 64B contiguous per instr; 4 waves' duplicate reads hit L2),
// converts to bf16 in-reg, B-fragments from L2-resident wp1. Waves free-run.
__global__ __launch_bounds__(256, 3) void kg0(
    const float* __restrict__ ft, const float* __restrict__ fi,
    const __hip_bfloat16* __restrict__ wp,
    float* __restrict__ out, int N)
{
    const int t = threadIdx.x;
    const int lane = t & 63;
    const int w = t >> 6;
    const int m0 = blockIdx.x * 64;
    const int g = lane >> 4;
    const int rl = lane & 15;

    f32x4 acc[4][4];
#pragma unroll
    for (int i = 0; i < 4; ++i)
#pragma unroll
        for (int j = 0; j < 4; ++j) acc[i][j] = (f32x4){0.f, 0.f, 0.f, 0.f};

    const short* wpb = (const short*)wp + ((size_t)w * 64 + rl) * 32 + g * 8;

#pragma unroll 1
    for (int seg = 0; seg < 2; ++seg) {
        const float* __restrict__ A = seg ? fi : ft;
        const int K = seg ? 512 : 384;
        const int ns = seg ? 16 : 12;
        const int ksb = seg ? 12 : 0;
        const float* rp[4];
#pragma unroll
        for (int fr = 0; fr < 4; ++fr) {
            int grow = m0 + fr * 16 + rl;
            if (grow >= N) grow = m0;
            rp[fr] = A + (size_t)grow * K + g * 8;
        }
#pragma unroll 1
        for (int s = 0; s < ns; ++s) {
            short8 af[4];
#pragma unroll
            for (int fr = 0; fr < 4; ++fr) {
                const float* ap = rp[fr] + s * 32;
                f32x4 lo = *(const f32x4*)ap;
                f32x4 hi = *(const f32x4*)(ap + 4);
                union { short8 s8; unsigned u[4]; } cv;
                cv.u[0] = bfpk(lo[0], lo[1]);
                cv.u[1] = bfpk(lo[2], lo[3]);
                cv.u[2] = bfpk(hi[0], hi[1]);
                cv.u[3] = bfpk(hi[2], hi[3]);
                af[fr] = cv.s8;
            }
            short8 bf[4];
            const short* bp = wpb + (size_t)(ksb + s) * 256 * 32;
#pragma unroll
            for (int fc = 0; fc < 4; ++fc)
                bf[fc] = *(const short8*)(bp + fc * 16 * 32);
#pragma unroll
            for (int fr = 0; fr < 4; ++fr)
#pragma unroll
                for (int fc = 0; fc < 4; ++fc)
                    acc[fr][fc] = __builtin_amdgcn_mfma_f32_16x16x32_bf16(af[fr], bf[fc], acc[fr][fc], 0, 0, 0);
        }
    }

    const int cbase = w * 64;
#pragma unroll
    for (int fr = 0; fr < 4; ++fr)
#pragma unroll
        for (int reg = 0; reg < 4; ++reg) {
            int grow = m0 + fr * 16 + g * 4 + reg;
            if (grow >= N) continue;
#pragma unroll
            for (int fc = 0; fc < 4; ++fc) {
                float vv = acc[fr][fc][reg];
                if (grow == 0) vv = 0.f;
                out[(size_t)grow * 256 + cbase + fc * 16 + rl] = vv;
            }
        }
}

// kg1: out = LN(h0 + S@wp2), row 0 zeroed. h0in aliases out.
// A-fragments read DIRECTLY from S_frag (written by k2 in fragment layout):
// lane-contiguous 256B runs, bf16, no conversion, NO LDS in K-loop, no barriers
// (one __syncthreads for the LN cross-wave reduce only).
__global__ __launch_bounds__(256, 4) void kg1(
    const __hip_bfloat16* __restrict__ Sf,
    const __hip_bfloat16* __restrict__ wp,
    const float* h0in, const float* __restrict__ gamma,
    const float* __restrict__ beta, float* __restrict__ out, int N)
{
    __shared__ float redS[64][4];
    __shared__ float redQ[64][4];

    const int t = threadIdx.x;
    const int lane = t & 63;
    const int w = t >> 6;
    const int rb = blockIdx.x;
    const int m0 = rb * 64;
    const int g = lane >> 4;
    const int rl = lane & 15;

    f32x4 acc[4][4];
#pragma unroll
    for (int i = 0; i < 4; ++i)
#pragma unroll
        for (int j = 0; j < 4; ++j) acc[i][j] = (f32x4){0.f, 0.f, 0.f, 0.f};

    const short* Ab = (const short*)(Sf + (size_t)rb * (24 * 256 * 8)) + ((size_t)g * 64 + rl) * 8;
    const short* wpb = (const short*)wp + ((size_t)w * 64 + rl) * 32 + g * 8;

#pragma unroll 1
    for (int ks = 0; ks < 24; ++ks) {
        short8 af[4];
        const short* ap = Ab + (size_t)ks * 256 * 8;
#pragma unroll
        for (int fr = 0; fr < 4; ++fr)
            af[fr] = *(const short8*)(ap + fr * 16 * 8);
        short8 bf[4];
        const short* bp = wpb + (size_t)ks * 256 * 32;
#pragma unroll
        for (int fc = 0; fc < 4; ++fc)
            bf[fc] = *(const short8*)(bp + fc * 16 * 32);
#pragma unroll
        for (int fr = 0; fr < 4; ++fr)
#pragma unroll
            for (int fc = 0; fc < 4; ++fc)
                acc[fr][fc] = __builtin_amdgcn_mfma_f32_16x16x32_bf16(af[fr], bf[fc], acc[fr][fc], 0, 0, 0);
    }

    const int cbase = w * 64;
    // x = acc + h0 (same-thread read-before-write; out aliases h0in)
#pragma unroll
    for (int fr = 0; fr < 4; ++fr)
#pragma unroll
        for (int reg = 0; reg < 4; ++reg) {
            int grow = m0 + fr * 16 + g * 4 + reg;
            if (grow < N) {
#pragma unroll
                for (int fc = 0; fc < 4; ++fc)
                    acc[fr][fc][reg] += h0in[(size_t)grow * 256 + cbase + fc * 16 + rl];
            }
        }
#pragma unroll
    for (int fr = 0; fr < 4; ++fr)
#pragma unroll
        for (int reg = 0; reg < 4; ++reg) {
            float s = 0.f, q = 0.f;
#pragma unroll
            for (int fc = 0; fc < 4; ++fc) {
                float vv = acc[fr][fc][reg];
                s += vv; q += vv * vv;
            }
#pragma unroll
            for (int off = 1; off < 16; off <<= 1) {
                s += __shfl_xor(s, off, 64);
                q += __shfl_xor(q, off, 64);
            }
            if (rl == 0) {
                int rlidx = fr * 16 + g * 4 + reg;
                redS[rlidx][w] = s;
                redQ[rlidx][w] = q;
            }
        }
    __syncthreads();
    float g4[4], b4[4];
#pragma unroll
    for (int fc = 0; fc < 4; ++fc) {
        g4[fc] = gamma[cbase + fc * 16 + rl];
        b4[fc] = beta[cbase + fc * 16 + rl];
    }
#pragma unroll
    for (int fr = 0; fr < 4; ++fr)
#pragma unroll
        for (int reg = 0; reg < 4; ++reg) {
            int rlidx = fr * 16 + g * 4 + reg;
            int grow = m0 + rlidx;
            if (grow >= N) continue;
            float s = redS[rlidx][0] + redS[rlidx][1] + redS[rlidx][2] + redS[rlidx][3];
            float q = redQ[rlidx][0] + redQ[rlidx][1] + redQ[rlidx][2] + redQ[rlidx][3];
            float mu  = s * (1.f / 256.f);
            float var = q * (1.f / 256.f) - mu * mu;
            float rstd = rsqrtf(var + LN_EPS);
#pragma unroll
            for (int fc = 0; fc < 4; ++fc) {
                float vv = (acc[fr][fc][reg] - mu) * rstd * g4[fc] + b4[fc];
                if (grow == 0) vv = 0.f;
                out[(size_t)grow * 256 + cbase + fc * 16 + rl] = vv;
            }
        }
}

extern "C" void kernel_launch(void* const* d_in, const int* in_sizes, int n_in,
                              void* d_out, int out_size, void* d_ws, size_t ws_size,
                              hipStream_t stream) {
    const int N = in_sizes[0] / 384;   // 100000
    const int E = in_sizes[7];         // 300000
    const float* ft    = (const float*)d_in[0];
    const float* fi    = (const float*)d_in[1];
    const float* wt    = (const float*)d_in[2];
    const float* wi    = (const float*)d_in[3];
    const float* wrel  = (const float*)d_in[4];
    const float* gamma = (const float*)d_in[5];
    const float* beta  = (const float*)d_in[6];
    const float* ew    = (const float*)d_in[7];
    const int*   eidx  = (const int*)d_in[8];
    const int*   etype = (const int*)d_in[9];
    float* out = (float*)d_out;

    const int NRB = (N + 63) / 64;                       // 1563 row-blocks
    // ws layout: S_frag bf16 [NRB][24][4][64][8] | head int[N] | next int[E] | wp1 | wp2
    __hip_bfloat16* Sf = (__hip_bfloat16*)d_ws;
    int* head = (int*)((char*)d_ws + (size_t)NRB * 24 * 256 * 8 * 2);
    int* nxt  = head + N;
    __hip_bfloat16* wp1 = (__hip_bfloat16*)(nxt + E);
    __hip_bfloat16* wp2 = wp1 + WP1_ELEMS;

    hipMemsetAsync(head, 0xFF, (size_t)N * sizeof(int), stream);   // head = -1

    kpack<<<(WP1_ELEMS + WP2_ELEMS + 255) / 256, 256, 0, stream>>>(wt, wi, wrel, wp1, wp2);

    kchain<<<(E + 255) / 256, 256, 0, stream>>>(eidx + E, head, nxt, E);

    kg0<<<NRB, 256, 0, stream>>>(ft, fi, wp1, out, N);

    k2_gather<<<(N + 7) / 8, 512, 0, stream>>>(out, eidx, etype, ew, head, nxt, Sf, N);

    kg1<<<NRB, 256, 0, stream>>>(Sf, wp2, out, gamma, beta, out, N);
}

// Round 10
// 556.859 us; speedup vs baseline: 1.0486x; 1.0486x over previous
//
#include <hip/hip_runtime.h>
#include <hip/hip_bf16.h>

#define HID 256
#define LN_EPS 1e-5f
#define DENOM_EPS 1e-8f

typedef __attribute__((ext_vector_type(8))) short short8;
typedef __attribute__((ext_vector_type(4))) float f32x4;

#define WP1_ELEMS (28 * 256 * 32)   // K=896 packed, pre-scaled by 0.5
#define WP2_ELEMS (24 * 256 * 32)   // K=768 (3 rels x 256)

__device__ inline unsigned bfpk(float x, float y) {
    __hip_bfloat162 h = __float22bfloat162_rn(make_float2(x, y));
    return *reinterpret_cast<unsigned*>(&h);
}

// Pack weights into fragment-native layout: wp[ks][col][kk] = W[ks*32+kk][col] (*0.5 for wp1)
__global__ __launch_bounds__(256) void kpack(
    const float* __restrict__ wt, const float* __restrict__ wi,
    const float* __restrict__ wrel,
    __hip_bfloat16* __restrict__ wp1, __hip_bfloat16* __restrict__ wp2)
{
    int idx = blockIdx.x * 256 + threadIdx.x;
    if (idx < WP1_ELEMS) {
        int kk = idx & 31, col = (idx >> 5) & 255, ks = idx >> 13;
        int k = ks * 32 + kk;
        float v = (k < 384) ? wt[k * 256 + col] : wi[(k - 384) * 256 + col];
        wp1[idx] = __float2bfloat16(v * 0.5f);
    } else {
        int j = idx - WP1_ELEMS;
        if (j < WP2_ELEMS) {
            int kk = j & 31, col = (j >> 5) & 255, ks = j >> 13;
            int k = ks * 32 + kk;                 // wrel flat [768][256]
            wp2[j] = __float2bfloat16(wrel[k * 256 + col]);
        }
    }
}

// Build per-dst edge chains: next[e] = atomicExch(head[dst], e). head pre-inited to -1.
__global__ __launch_bounds__(256) void kchain(
    const int* __restrict__ edst, int* __restrict__ head, int* __restrict__ nxt, int E)
{
    int e = blockIdx.x * 256 + threadIdx.x;
    if (e < E) nxt[e] = atomicExch(&head[edst[e]], e);
}

// k2: 8 waves/block, wave = one dst node. Walk chain, acc[rel] += w*h0[src],
// write S in MFMA-FRAGMENT layout: S_frag[rb][ks][g][r][8e] bf16,
// rb=d>>6, r=d&63; lane l covers cols c=l*4..l*4+3 per rel:
// ks=rel*8+(l>>3), g=(l&7)>>1, e0=(l&1)*4 -> one uint2 store per rel.
__global__ __launch_bounds__(512) void k2_gather(
    const float* __restrict__ h0, const int* __restrict__ esrc,
    const int* __restrict__ etype, const float* __restrict__ ew,
    const int* __restrict__ head, const int* __restrict__ nxt,
    __hip_bfloat16* __restrict__ Sf, int N)
{
    int w = threadIdx.x >> 6;
    int lane = threadIdx.x & 63;
    int d = blockIdx.x * 8 + w;
    if (d >= N) return;

    f32x4 a0 = {0.f, 0.f, 0.f, 0.f}, a1 = a0, a2 = a0;
    float d0 = 0.f, d1 = 0.f, d2 = 0.f;

    int e = head[d];
    while (e >= 0) {
        int src = esrc[e];
        int ty = etype[e];       // wave-uniform
        float w_ = ew[e];
        const float4 h = *(const float4*)(h0 + (size_t)src * HID + lane * 4);
        f32x4 hw = {w_ * h.x, w_ * h.y, w_ * h.z, w_ * h.w};
        if (ty == 0)      { a0 += hw; d0 += w_; }
        else if (ty == 1) { a1 += hw; d1 += w_; }
        else              { a2 += hw; d2 += w_; }
        e = nxt[e];
    }

    float i0 = 1.0f / fmaxf(d0, DENOM_EPS);
    float i1 = 1.0f / fmaxf(d1, DENOM_EPS);
    float i2 = 1.0f / fmaxf(d2, DENOM_EPS);

    const int rb = d >> 6, r = d & 63;
    const int g = (lane & 7) >> 1;
    const int e0 = (lane & 1) * 4;
    __hip_bfloat16* base = Sf + (size_t)rb * (24 * 256 * 8);
#pragma unroll
    for (int rel = 0; rel < 3; ++rel) {
        const f32x4& a = rel == 0 ? a0 : (rel == 1 ? a1 : a2);
        const float iv = rel == 0 ? i0 : (rel == 1 ? i1 : i2);
        int ks = rel * 8 + (lane >> 3);
        size_t off = ((size_t)ks * 256 + g * 64 + r) * 8 + e0;
        uint2 p = make_uint2(bfpk(a[0] * iv, a[1] * iv), bfpk(a[2] * iv, a[3] * iv));
        *(uint2*)(base + off) = p;
    }
}

// kg0: h0 = ft@wp1a + fi@wp1b (0.5 pre-folded), row 0 zeroed.
// Block = 32 rows x 256 cols, 4 waves (wave = 64-col strip), wave tile 32x64.
// NO LDS, NO BARRIERS. Explicit register double-buffering: named ping-pong sets
// (raA/raB for A, bfA/bfB for B) reloaded for step s+2 right after consumption
// -> load->use distance = 1 full half-iteration, x4 waves/SIMD TLP. No vmcnt(0)
// drains anywhere, so the compiler's natural waitcnt placement pipelines.
__global__ __launch_bounds__(256, 4) void kg0(
    const float* __restrict__ ft, const float* __restrict__ fi,
    const __hip_bfloat16* __restrict__ wp,
    float* __restrict__ out, int N)
{
    const int t = threadIdx.x;
    const int lane = t & 63;
    const int w = t >> 6;
    const int m0 = blockIdx.x * 32;
    const int g = lane >> 4;
    const int rl = lane & 15;

    f32x4 acc[2][4];
#pragma unroll
    for (int i = 0; i < 2; ++i)
#pragma unroll
        for (int j = 0; j < 4; ++j) acc[i][j] = (f32x4){0.f, 0.f, 0.f, 0.f};

    const float* rpT[2];
    const float* rpI[2];
#pragma unroll
    for (int fr = 0; fr < 2; ++fr) {
        int grow = m0 + fr * 16 + rl;
        if (grow >= N) grow = m0;
        rpT[fr] = ft + (size_t)grow * 384 + g * 8;
        rpI[fr] = fi + (size_t)grow * 512 + g * 8;
    }
    const short* wpb = (const short*)wp + ((size_t)w * 64 + rl) * 32 + g * 8;

    auto loadA = [&](f32x4 (&ra)[2][2], int s) {
#pragma unroll
        for (int fr = 0; fr < 2; ++fr) {
            const float* p = (s < 12) ? rpT[fr] + s * 32 : rpI[fr] + (s - 12) * 32;
            ra[fr][0] = *(const f32x4*)p;
            ra[fr][1] = *(const f32x4*)(p + 4);
        }
    };
    auto loadB = [&](short8 (&bf)[4], int s) {
        const short* bp = wpb + (size_t)s * 8192;
#pragma unroll
        for (int fc = 0; fc < 4; ++fc) bf[fc] = *(const short8*)(bp + fc * 512);
    };
    auto cvtA = [&](short8 (&af)[2], f32x4 (&ra)[2][2]) {
#pragma unroll
        for (int fr = 0; fr < 2; ++fr) {
            union { short8 s8; unsigned u[4]; } cv;
            cv.u[0] = bfpk(ra[fr][0][0], ra[fr][0][1]);
            cv.u[1] = bfpk(ra[fr][0][2], ra[fr][0][3]);
            cv.u[2] = bfpk(ra[fr][1][0], ra[fr][1][1]);
            cv.u[3] = bfpk(ra[fr][1][2], ra[fr][1][3]);
            af[fr] = cv.s8;
        }
    };
    auto domfma = [&](short8 (&af)[2], short8 (&bf)[4]) {
#pragma unroll
        for (int fr = 0; fr < 2; ++fr)
#pragma unroll
            for (int fc = 0; fc < 4; ++fc)
                acc[fr][fc] = __builtin_amdgcn_mfma_f32_16x16x32_bf16(af[fr], bf[fc], acc[fr][fc], 0, 0, 0);
    };

    f32x4 raA[2][2], raB[2][2];
    short8 bfA[4], bfB[4];
    loadA(raA, 0); loadB(bfA, 0);
    loadA(raB, 1); loadB(bfB, 1);

#pragma unroll 1
    for (int p = 0; p < 14; ++p) {
        const int s = 2 * p;
        short8 af[2];
        // even half: consume set A, refill for s+2
        cvtA(af, raA);
        if (s + 2 < 28) loadA(raA, s + 2);
        domfma(af, bfA);
        if (s + 2 < 28) loadB(bfA, s + 2);
        // odd half: consume set B, refill for s+3
        cvtA(af, raB);
        if (s + 3 < 28) loadA(raB, s + 3);
        domfma(af, bfB);
        if (s + 3 < 28) loadB(bfB, s + 3);
    }

    const int cbase = w * 64;
#pragma unroll
    for (int fr = 0; fr < 2; ++fr)
#pragma unroll
        for (int reg = 0; reg < 4; ++reg) {
            int grow = m0 + fr * 16 + g * 4 + reg;
            if (grow >= N) continue;
#pragma unroll
            for (int fc = 0; fc < 4; ++fc) {
                float vv = acc[fr][fc][reg];
                if (grow == 0) vv = 0.f;
                out[(size_t)grow * 256 + cbase + fc * 16 + rl] = vv;
            }
        }
}

// kg1: out = LN(h0 + S@wp2), row 0 zeroed. h0in aliases out.
// Block = 32 rows, 4 waves, wave tile 32x64. A read directly from fragment-layout
// S (bf16, coalesced 256B runs, no conversion). Same ping-pong register pipeline,
// no LDS in K-loop, single __syncthreads for the LN cross-wave reduce.
__global__ __launch_bounds__(256, 4) void kg1(
    const __hip_bfloat16* __restrict__ Sf,
    const __hip_bfloat16* __restrict__ wp,
    const float* h0in, const float* __restrict__ gamma,
    const float* __restrict__ beta, float* __restrict__ out, int N)
{
    __shared__ float redS[32][4];
    __shared__ float redQ[32][4];

    const int t = threadIdx.x;
    const int lane = t & 63;
    const int w = t >> 6;
    const int b = blockIdx.x;
    const int m0 = b * 32;
    const int rb = b >> 1;
    const int ro = (b & 1) * 32;
    const int g = lane >> 4;
    const int rl = lane & 15;

    f32x4 acc[2][4];
#pragma unroll
    for (int i = 0; i < 2; ++i)
#pragma unroll
        for (int j = 0; j < 4; ++j) acc[i][j] = (f32x4){0.f, 0.f, 0.f, 0.f};

    // S_frag element (ks,g,r,e) at ((ks*4+g)*64 + r)*8 + e;  r = ro + fr*16 + rl
    const short* Ab = (const short*)Sf + (size_t)rb * (24 * 256 * 8)
                    + ((size_t)g * 64 + ro + rl) * 8;
    const short* wpb = (const short*)wp + ((size_t)w * 64 + rl) * 32 + g * 8;

    auto loadA = [&](short8 (&af)[2], int ks) {
        const short* p = Ab + (size_t)ks * 2048;
        af[0] = *(const short8*)p;
        af[1] = *(const short8*)(p + 128);
    };
    auto loadB = [&](short8 (&bf)[4], int ks) {
        const short* bp = wpb + (size_t)ks * 8192;
#pragma unroll
        for (int fc = 0; fc < 4; ++fc) bf[fc] = *(const short8*)(bp + fc * 512);
    };
    auto domfma = [&](short8 (&af)[2], short8 (&bf)[4]) {
#pragma unroll
        for (int fr = 0; fr < 2; ++fr)
#pragma unroll
            for (int fc = 0; fc < 4; ++fc)
                acc[fr][fc] = __builtin_amdgcn_mfma_f32_16x16x32_bf16(af[fr], bf[fc], acc[fr][fc], 0, 0, 0);
    };

    short8 aA[2], aB[2], bA[4], bB[4];
    loadA(aA, 0); loadB(bA, 0);
    loadA(aB, 1); loadB(bB, 1);

#pragma unroll 1
    for (int p = 0; p < 12; ++p) {
        const int s = 2 * p;
        domfma(aA, bA);
        if (s + 2 < 24) { loadA(aA, s + 2); loadB(bA, s + 2); }
        domfma(aB, bB);
        if (s + 3 < 24) { loadA(aB, s + 3); loadB(bB, s + 3); }
    }

    const int cbase = w * 64;
    // x = acc + h0 (same-thread read-before-write; out aliases h0in)
#pragma unroll
    for (int fr = 0; fr < 2; ++fr)
#pragma unroll
        for (int reg = 0; reg < 4; ++reg) {
            int grow = m0 + fr * 16 + g * 4 + reg;
            if (grow < N) {
#pragma unroll
                for (int fc = 0; fc < 4; ++fc)
                    acc[fr][fc][reg] += h0in[(size_t)grow * 256 + cbase + fc * 16 + rl];
            }
        }
#pragma unroll
    for (int fr = 0; fr < 2; ++fr)
#pragma unroll
        for (int reg = 0; reg < 4; ++reg) {
            float s = 0.f, q = 0.f;
#pragma unroll
            for (int fc = 0; fc < 4; ++fc) {
                float vv = acc[fr][fc][reg];
                s += vv; q += vv * vv;
            }
#pragma unroll
            for (int off = 1; off < 16; off <<= 1) {
                s += __shfl_xor(s, off, 64);
                q += __shfl_xor(q, off, 64);
            }
            if (rl == 0) {
                int rlidx = fr * 16 + g * 4 + reg;
                redS[rlidx][w] = s;
                redQ[rlidx][w] = q;
            }
        }
    __syncthreads();
    float g4[4], b4[4];
#pragma unroll
    for (int fc = 0; fc < 4; ++fc) {
        g4[fc] = gamma[cbase + fc * 16 + rl];
        b4[fc] = beta[cbase + fc * 16 + rl];
    }
#pragma unroll
    for (int fr = 0; fr < 2; ++fr)
#pragma unroll
        for (int reg = 0; reg < 4; ++reg) {
            int rlidx = fr * 16 + g * 4 + reg;
            int grow = m0 + rlidx;
            if (grow >= N) continue;
            float s = redS[rlidx][0] + redS[rlidx][1] + redS[rlidx][2] + redS[rlidx][3];
            float q = redQ[rlidx][0] + redQ[rlidx][1] + redQ[rlidx][2] + redQ[rlidx][3];
            float mu  = s * (1.f / 256.f);
            float var = q * (1.f / 256.f) - mu * mu;
            float rstd = rsqrtf(var + LN_EPS);
#pragma unroll
            for (int fc = 0; fc < 4; ++fc) {
                float vv = (acc[fr][fc][reg] - mu) * rstd * g4[fc] + b4[fc];
                if (grow == 0) vv = 0.f;
                out[(size_t)grow * 256 + cbase + fc * 16 + rl] = vv;
            }
        }
}

extern "C" void kernel_launch(void* const* d_in, const int* in_sizes, int n_in,
                              void* d_out, int out_size, void* d_ws, size_t ws_size,
                              hipStream_t stream) {
    const int N = in_sizes[0] / 384;   // 100000
    const int E = in_sizes[7];         // 300000
    const float* ft    = (const float*)d_in[0];
    const float* fi    = (const float*)d_in[1];
    const float* wt    = (const float*)d_in[2];
    const float* wi    = (const float*)d_in[3];
    const float* wrel  = (const float*)d_in[4];
    const float* gamma = (const float*)d_in[5];
    const float* beta  = (const float*)d_in[6];
    const float* ew    = (const float*)d_in[7];
    const int*   eidx  = (const int*)d_in[8];
    const int*   etype = (const int*)d_in[9];
    float* out = (float*)d_out;

    const int NRB = (N + 63) / 64;                       // 1563 row-blocks (64-row)
    // ws layout: S_frag bf16 [NRB][24][4][64][8] | head int[N] | next int[E] | wp1 | wp2
    __hip_bfloat16* Sf = (__hip_bfloat16*)d_ws;
    int* head = (int*)((char*)d_ws + (size_t)NRB * 24 * 256 * 8 * 2);
    int* nxt  = head + N;
    __hip_bfloat16* wp1 = (__hip_bfloat16*)(nxt + E);
    __hip_bfloat16* wp2 = wp1 + WP1_ELEMS;

    hipMemsetAsync(head, 0xFF, (size_t)N * sizeof(int), stream);   // head = -1

    kpack<<<(WP1_ELEMS + WP2_ELEMS + 255) / 256, 256, 0, stream>>>(wt, wi, wrel, wp1, wp2);

    kchain<<<(E + 255) / 256, 256, 0, stream>>>(eidx + E, head, nxt, E);

    const int g32 = (N + 31) / 32;                       // 3125 (exact, no tail)
    kg0<<<g32, 256, 0, stream>>>(ft, fi, wp1, out, N);

    k2_gather<<<(N + 7) / 8, 512, 0, stream>>>(out, eidx, etype, ew, head, nxt, Sf, N);

    kg1<<<g32, 256, 0, stream>>>(Sf, wp2, out, gamma, beta, out, N);
}

// Round 11
// 435.360 us; speedup vs baseline: 1.3413x; 1.2791x over previous
//
#include <hip/hip_runtime.h>
#include <hip/hip_bf16.h>

#define HID 256
#define LN_EPS 1e-5f
#define DENOM_EPS 1e-8f

typedef __attribute__((ext_vector_type(8))) short short8;
typedef __attribute__((ext_vector_type(4))) float f32x4;

#define WP1_ELEMS (28 * 256 * 32)   // K=896 packed (32k steps), pre-scaled by 0.5
#define WP2_ELEMS (24 * 256 * 32)   // K=768

__device__ inline unsigned bfpk(float x, float y) {
    __hip_bfloat162 h = __float22bfloat162_rn(make_float2(x, y));
    return *reinterpret_cast<unsigned*>(&h);
}

__device__ inline void gld16(const void* g, void* l) {
    __builtin_amdgcn_global_load_lds(
        (const __attribute__((address_space(1))) void*)g,
        (__attribute__((address_space(3))) void*)l, 16, 0, 0);
}

// Pack weights: wp[ks32][col][kk] = W[ks32*32+kk][col] (*0.5 for wp1)
__global__ __launch_bounds__(256) void kpack(
    const float* __restrict__ wt, const float* __restrict__ wi,
    const float* __restrict__ wrel,
    __hip_bfloat16* __restrict__ wp1, __hip_bfloat16* __restrict__ wp2)
{
    int idx = blockIdx.x * 256 + threadIdx.x;
    if (idx < WP1_ELEMS) {
        int kk = idx & 31, col = (idx >> 5) & 255, ks = idx >> 13;
        int k = ks * 32 + kk;
        float v = (k < 384) ? wt[k * 256 + col] : wi[(k - 384) * 256 + col];
        wp1[idx] = __float2bfloat16(v * 0.5f);
    } else {
        int j = idx - WP1_ELEMS;
        if (j < WP2_ELEMS) {
            int kk = j & 31, col = (j >> 5) & 255, ks = j >> 13;
            int k = ks * 32 + kk;
            wp2[j] = __float2bfloat16(wrel[k * 256 + col]);
        }
    }
}

__global__ __launch_bounds__(256) void kchain(
    const int* __restrict__ edst, int* __restrict__ head, int* __restrict__ nxt, int E)
{
    int e = blockIdx.x * 256 + threadIdx.x;
    if (e < E) nxt[e] = atomicExch(&head[edst[e]], e);
}

// One wave per dst node: walk chain, acc[rel] += w*h0[src];
// S[d][rel*256+c] = bf16(acc[rel][c] / max(denom[rel], eps)).  Row-major [N][768].
__global__ __launch_bounds__(512) void k2_gather(
    const float* __restrict__ h0, const int* __restrict__ esrc,
    const int* __restrict__ etype, const float* __restrict__ ew,
    const int* __restrict__ head, const int* __restrict__ nxt,
    __hip_bfloat16* __restrict__ S, int N)
{
    int w = threadIdx.x >> 6;
    int lane = threadIdx.x & 63;
    int d = blockIdx.x * 8 + w;
    if (d >= N) return;

    f32x4 a0 = {0.f, 0.f, 0.f, 0.f}, a1 = a0, a2 = a0;
    float d0 = 0.f, d1 = 0.f, d2 = 0.f;

    int e = head[d];
    while (e >= 0) {
        int src = esrc[e];
        int ty = etype[e];
        float w_ = ew[e];
        const float4 h = *(const float4*)(h0 + (size_t)src * HID + lane * 4);
        f32x4 hw = {w_ * h.x, w_ * h.y, w_ * h.z, w_ * h.w};
        if (ty == 0)      { a0 += hw; d0 += w_; }
        else if (ty == 1) { a1 += hw; d1 += w_; }
        else              { a2 += hw; d2 += w_; }
        e = nxt[e];
    }

    float i0 = 1.0f / fmaxf(d0, DENOM_EPS);
    float i1 = 1.0f / fmaxf(d1, DENOM_EPS);
    float i2 = 1.0f / fmaxf(d2, DENOM_EPS);
    __hip_bfloat16* row = S + (size_t)d * 768;
    uint2 p;
    p = make_uint2(bfpk(a0[0] * i0, a0[1] * i0), bfpk(a0[2] * i0, a0[3] * i0));
    *(uint2*)(row + 0   + lane * 4) = p;
    p = make_uint2(bfpk(a1[0] * i1, a1[1] * i1), bfpk(a1[2] * i1, a1[3] * i1));
    *(uint2*)(row + 256 + lane * 4) = p;
    p = make_uint2(bfpk(a2[0] * i2, a2[1] * i2), bfpk(a2[2] * i2, a2[3] * i2));
    *(uint2*)(row + 512 + lane * 4) = p;
}

// kg0: h0 = ft@wp1a + fi@wp1b (0.5 pre-folded), row 0 zeroed.
// 64x256 tile, 4 waves, BK=64 -> 14 K-steps, 32 MFMA/wave/step (2x R8's
// MFMA-per-barrier). A staged f32 via global_load_lds, double-buffered,
// 1 raw barrier/step, counted vmcnt (drain stage(ks), keep B(ks)=8).
// LDS row = 256B = 16 chunks; swizzle c^=(r&15) (inverse on source, fwd on read).
__global__ __launch_bounds__(256, 3) void kg0(
    const float* __restrict__ ft, const float* __restrict__ fi,
    const __hip_bfloat16* __restrict__ wp,
    float* __restrict__ out, int N)
{
    __shared__ __align__(16) unsigned char As[2][16384];
    const int t = threadIdx.x;
    const int lane = t & 63;
    const int w = t >> 6;
    const int m0 = blockIdx.x * 64;
    const int g = lane >> 4;
    const int rl = lane & 15;

    auto stageA = [&](int ks, int buf) {
#pragma unroll
        for (int i = 0; i < 4; ++i) {
            int r = i * 16 + w * 4 + (lane >> 4);
            int grow = m0 + r; if (grow >= N) grow = m0;
            int cl = (lane & 15) ^ (r & 15);
            const float* src = (ks < 6)
                ? ft + (size_t)grow * 384 + ks * 64 + cl * 4
                : fi + (size_t)grow * 512 + (ks - 6) * 64 + cl * 4;
            gld16(src, As[buf] + i * 4096 + w * 1024);
        }
    };
    auto loadB = [&](short8 (&bf)[8], int ks) {
#pragma unroll
        for (int s = 0; s < 2; ++s)
#pragma unroll
            for (int fc = 0; fc < 4; ++fc)
                bf[s * 4 + fc] = *(const short8*)((const short*)wp +
                    (size_t)((2 * ks + s) * 256 + w * 64 + fc * 16 + rl) * 32 + g * 8);
    };

    f32x4 acc[4][4];
#pragma unroll
    for (int i = 0; i < 4; ++i)
#pragma unroll
        for (int j = 0; j < 4; ++j) acc[i][j] = (f32x4){0.f, 0.f, 0.f, 0.f};

    auto compute = [&](int buf, short8 (&bf)[8]) {
#pragma unroll
        for (int s = 0; s < 2; ++s) {
            short8 af[4];
#pragma unroll
            for (int fr = 0; fr < 4; ++fr) {
                int r = fr * 16 + rl;
                int c0 = (s * 8 + g * 2) ^ (r & 15);
                int c1 = (s * 8 + g * 2 + 1) ^ (r & 15);
                f32x4 lo = *(const f32x4*)(As[buf] + r * 256 + c0 * 16);
                f32x4 hi = *(const f32x4*)(As[buf] + r * 256 + c1 * 16);
                union { short8 s8; unsigned u[4]; } cv;
                cv.u[0] = bfpk(lo[0], lo[1]);
                cv.u[1] = bfpk(lo[2], lo[3]);
                cv.u[2] = bfpk(hi[0], hi[1]);
                cv.u[3] = bfpk(hi[2], hi[3]);
                af[fr] = cv.s8;
            }
#pragma unroll
            for (int fr = 0; fr < 4; ++fr)
#pragma unroll
                for (int fc = 0; fc < 4; ++fc)
                    acc[fr][fc] = __builtin_amdgcn_mfma_f32_16x16x32_bf16(af[fr], bf[s * 4 + fc], acc[fr][fc], 0, 0, 0);
        }
    };

    short8 bfA[8], bfB[8];
    stageA(0, 0);
    loadB(bfA, 0);

#pragma unroll 1
    for (int p = 0; p < 7; ++p) {
        const int ks = 2 * p;
        // even half: compute ks
        asm volatile("s_waitcnt vmcnt(8)" ::: "memory");
        __builtin_amdgcn_s_barrier();
        __builtin_amdgcn_sched_barrier(0);
        stageA(ks + 1, 1);
        loadB(bfB, ks + 1);
        compute(0, bfA);
        // odd half: compute ks+1
        if (p == 6) asm volatile("s_waitcnt vmcnt(0)" ::: "memory");
        else        asm volatile("s_waitcnt vmcnt(8)" ::: "memory");
        __builtin_amdgcn_s_barrier();
        __builtin_amdgcn_sched_barrier(0);
        if (ks + 2 < 14) { stageA(ks + 2, 0); loadB(bfA, ks + 2); }
        compute(1, bfB);
    }

    const int cbase = w * 64;
#pragma unroll
    for (int fr = 0; fr < 4; ++fr)
#pragma unroll
        for (int reg = 0; reg < 4; ++reg) {
            int grow = m0 + fr * 16 + g * 4 + reg;
            if (grow >= N) continue;
#pragma unroll
            for (int fc = 0; fc < 4; ++fc) {
                float vv = acc[fr][fc][reg];
                if (grow == 0) vv = 0.f;
                out[(size_t)grow * 256 + cbase + fc * 16 + rl] = vv;
            }
        }
}

// kg1: out = LN(h0 + S@wp2), row 0 zeroed. h0in aliases out.
// Same structure, A bf16 [N][768], BK=64 -> 12 steps. LDS row = 128B = 8 chunks,
// swizzle c^=(r&7).
__global__ __launch_bounds__(256, 3) void kg1(
    const __hip_bfloat16* __restrict__ Sb,
    const __hip_bfloat16* __restrict__ wp,
    const float* h0in, const float* __restrict__ gamma,
    const float* __restrict__ beta, float* __restrict__ out, int N)
{
    __shared__ __align__(16) unsigned char As[2][8192];
    __shared__ float redS[64][4];
    __shared__ float redQ[64][4];

    const int t = threadIdx.x;
    const int lane = t & 63;
    const int w = t >> 6;
    const int m0 = blockIdx.x * 64;
    const int g = lane >> 4;
    const int rl = lane & 15;

    auto stageA = [&](int ks, int buf) {
#pragma unroll
        for (int i = 0; i < 2; ++i) {
            int r = i * 32 + w * 8 + (lane >> 3);
            int grow = m0 + r; if (grow >= N) grow = m0;
            int cl = (lane & 7) ^ (r & 7);
            const __hip_bfloat16* src = Sb + (size_t)grow * 768 + ks * 64 + cl * 8;
            gld16(src, As[buf] + i * 4096 + w * 1024);
        }
    };
    auto loadB = [&](short8 (&bf)[8], int ks) {
#pragma unroll
        for (int s = 0; s < 2; ++s)
#pragma unroll
            for (int fc = 0; fc < 4; ++fc)
                bf[s * 4 + fc] = *(const short8*)((const short*)wp +
                    (size_t)((2 * ks + s) * 256 + w * 64 + fc * 16 + rl) * 32 + g * 8);
    };

    f32x4 acc[4][4];
#pragma unroll
    for (int i = 0; i < 4; ++i)
#pragma unroll
        for (int j = 0; j < 4; ++j) acc[i][j] = (f32x4){0.f, 0.f, 0.f, 0.f};

    auto compute = [&](int buf, short8 (&bf)[8]) {
#pragma unroll
        for (int s = 0; s < 2; ++s) {
            short8 af[4];
#pragma unroll
            for (int fr = 0; fr < 4; ++fr) {
                int r = fr * 16 + rl;
                int c = (s * 4 + g) ^ (r & 7);
                af[fr] = *(const short8*)(As[buf] + r * 128 + c * 16);
            }
#pragma unroll
            for (int fr = 0; fr < 4; ++fr)
#pragma unroll
                for (int fc = 0; fc < 4; ++fc)
                    acc[fr][fc] = __builtin_amdgcn_mfma_f32_16x16x32_bf16(af[fr], bf[s * 4 + fc], acc[fr][fc], 0, 0, 0);
        }
    };

    short8 bfA[8], bfB[8];
    stageA(0, 0);
    loadB(bfA, 0);

#pragma unroll 1
    for (int p = 0; p < 6; ++p) {
        const int ks = 2 * p;
        asm volatile("s_waitcnt vmcnt(8)" ::: "memory");
        __builtin_amdgcn_s_barrier();
        __builtin_amdgcn_sched_barrier(0);
        stageA(ks + 1, 1);
        loadB(bfB, ks + 1);
        compute(0, bfA);
        if (p == 5) asm volatile("s_waitcnt vmcnt(0)" ::: "memory");
        else        asm volatile("s_waitcnt vmcnt(8)" ::: "memory");
        __builtin_amdgcn_s_barrier();
        __builtin_amdgcn_sched_barrier(0);
        if (ks + 2 < 12) { stageA(ks + 2, 0); loadB(bfA, ks + 2); }
        compute(1, bfB);
    }

    const int cbase = w * 64;
#pragma unroll
    for (int fr = 0; fr < 4; ++fr)
#pragma unroll
        for (int reg = 0; reg < 4; ++reg) {
            int grow = m0 + fr * 16 + g * 4 + reg;
            if (grow < N) {
#pragma unroll
                for (int fc = 0; fc < 4; ++fc)
                    acc[fr][fc][reg] += h0in[(size_t)grow * 256 + cbase + fc * 16 + rl];
            }
        }
#pragma unroll
    for (int fr = 0; fr < 4; ++fr)
#pragma unroll
        for (int reg = 0; reg < 4; ++reg) {
            float s = 0.f, q = 0.f;
#pragma unroll
            for (int fc = 0; fc < 4; ++fc) {
                float vv = acc[fr][fc][reg];
                s += vv; q += vv * vv;
            }
#pragma unroll
            for (int off = 1; off < 16; off <<= 1) {
                s += __shfl_xor(s, off, 64);
                q += __shfl_xor(q, off, 64);
            }
            if (rl == 0) {
                int rlidx = fr * 16 + g * 4 + reg;
                redS[rlidx][w] = s;
                redQ[rlidx][w] = q;
            }
        }
    __syncthreads();
    float g4[4], b4[4];
#pragma unroll
    for (int fc = 0; fc < 4; ++fc) {
        g4[fc] = gamma[cbase + fc * 16 + rl];
        b4[fc] = beta[cbase + fc * 16 + rl];
    }
#pragma unroll
    for (int fr = 0; fr < 4; ++fr)
#pragma unroll
        for (int reg = 0; reg < 4; ++reg) {
            int rlidx = fr * 16 + g * 4 + reg;
            int grow = m0 + rlidx;
            if (grow >= N) continue;
            float s = redS[rlidx][0] + redS[rlidx][1] + redS[rlidx][2] + redS[rlidx][3];
            float q = redQ[rlidx][0] + redQ[rlidx][1] + redQ[rlidx][2] + redQ[rlidx][3];
            float mu  = s * (1.f / 256.f);
            float var = q * (1.f / 256.f) - mu * mu;
            float rstd = rsqrtf(var + LN_EPS);
#pragma unroll
            for (int fc = 0; fc < 4; ++fc) {
                float vv = (acc[fr][fc][reg] - mu) * rstd * g4[fc] + b4[fc];
                if (grow == 0) vv = 0.f;
                out[(size_t)grow * 256 + cbase + fc * 16 + rl] = vv;
            }
        }
}

extern "C" void kernel_launch(void* const* d_in, const int* in_sizes, int n_in,
                              void* d_out, int out_size, void* d_ws, size_t ws_size,
                              hipStream_t stream) {
    const int N = in_sizes[0] / 384;   // 100000
    const int E = in_sizes[7];         // 300000
    const float* ft    = (const float*)d_in[0];
    const float* fi    = (const float*)d_in[1];
    const float* wt    = (const float*)d_in[2];
    const float* wi    = (const float*)d_in[3];
    const float* wrel  = (const float*)d_in[4];
    const float* gamma = (const float*)d_in[5];
    const float* beta  = (const float*)d_in[6];
    const float* ew    = (const float*)d_in[7];
    const int*   eidx  = (const int*)d_in[8];
    const int*   etype = (const int*)d_in[9];
    float* out = (float*)d_out;

    // ws layout: S bf16 [N][768] | head int[N] | next int[E] | wp1 | wp2
    __hip_bfloat16* S = (__hip_bfloat16*)d_ws;
    int* head = (int*)((char*)d_ws + (size_t)N * 768 * 2);
    int* nxt  = head + N;
    __hip_bfloat16* wp1 = (__hip_bfloat16*)(nxt + E);
    __hip_bfloat16* wp2 = wp1 + WP1_ELEMS;

    hipMemsetAsync(head, 0xFF, (size_t)N * sizeof(int), stream);

    kpack<<<(WP1_ELEMS + WP2_ELEMS + 255) / 256, 256, 0, stream>>>(wt, wi, wrel, wp1, wp2);

    kchain<<<(E + 255) / 256, 256, 0, stream>>>(eidx + E, head, nxt, E);

    const int gblocks = (N + 63) / 64;                   // 1563
    kg0<<<gblocks, 256, 0, stream>>>(ft, fi, wp1, out, N);

    k2_gather<<<(N + 7) / 8, 512, 0, stream>>>(out, eidx, etype, ew, head, nxt, S, N);

    kg1<<<gblocks, 256, 0, stream>>>(S, wp2, out, gamma, beta, out, N);
}

// Round 12
// 410.056 us; speedup vs baseline: 1.4240x; 1.0617x over previous
//
#include <hip/hip_runtime.h>
#include <hip/hip_bf16.h>

#define HID 256
#define LN_EPS 1e-5f
#define DENOM_EPS 1e-8f

typedef __attribute__((ext_vector_type(8))) short short8;
typedef __attribute__((ext_vector_type(4))) float f32x4;

#define WP1_ELEMS (28 * 256 * 32)   // K=896 packed (32k steps), pre-scaled by 0.5
#define WP2_ELEMS (24 * 256 * 32)   // K=768 (3 rels x 256)

__device__ inline unsigned bfpk(float x, float y) {
    __hip_bfloat162 h = __float22bfloat162_rn(make_float2(x, y));
    return *reinterpret_cast<unsigned*>(&h);
}

__device__ inline void gld16(const void* g, void* l) {
    __builtin_amdgcn_global_load_lds(
        (const __attribute__((address_space(1))) void*)g,
        (__attribute__((address_space(3))) void*)l, 16, 0, 0);
}

__device__ inline f32x4 bf4_to_f32(uint2 p) {
    union { float f; unsigned u; } c;
    f32x4 r;
    c.u = (p.x & 0xFFFFu) << 16;  r[0] = c.f;
    c.u = (p.x & 0xFFFF0000u);    r[1] = c.f;
    c.u = (p.y & 0xFFFFu) << 16;  r[2] = c.f;
    c.u = (p.y & 0xFFFF0000u);    r[3] = c.f;
    return r;
}

// Pack weights: wp[ks32][col][kk] = W[ks32*32+kk][col] (*0.5 for wp1)
__global__ __launch_bounds__(256) void kpack(
    const float* __restrict__ wt, const float* __restrict__ wi,
    const float* __restrict__ wrel,
    __hip_bfloat16* __restrict__ wp1, __hip_bfloat16* __restrict__ wp2)
{
    int idx = blockIdx.x * 256 + threadIdx.x;
    if (idx < WP1_ELEMS) {
        int kk = idx & 31, col = (idx >> 5) & 255, ks = idx >> 13;
        int k = ks * 32 + kk;
        float v = (k < 384) ? wt[k * 256 + col] : wi[(k - 384) * 256 + col];
        wp1[idx] = __float2bfloat16(v * 0.5f);
    } else {
        int j = idx - WP1_ELEMS;
        if (j < WP2_ELEMS) {
            int kk = j & 31, col = (j >> 5) & 255, ks = j >> 13;
            int k = ks * 32 + kk;
            wp2[j] = __float2bfloat16(wrel[k * 256 + col]);
        }
    }
}

__global__ __launch_bounds__(256) void kchain(
    const int* __restrict__ edst, int* __restrict__ head, int* __restrict__ nxt, int E)
{
    int e = blockIdx.x * 256 + threadIdx.x;
    if (e < E) nxt[e] = atomicExch(&head[edst[e]], e);
}

// kg0f: GEMM1 (h0 = ft@wp1a + fi@wp1b, 0.5 pre-folded) with R8's proven
// staged/counted-vmcnt loop, THEN fused GEMM2: Y[rel] = h0 @ W_rel for rel=0..2,
// with h0 held in a swizzled LDS tile (one barrier, then barrier-free K-steps,
// B from L2-resident wp2). Writes h0 as bf16 (for residual) + Y[3] bf16.
// Row 0 of h0 zeroed (in tile AND h0b) so Y[.][0]=0 automatically.
__global__ __launch_bounds__(256, 3) void kg0f(
    const float* __restrict__ ft, const float* __restrict__ fi,
    const __hip_bfloat16* __restrict__ wp1,
    const __hip_bfloat16* __restrict__ wp2,
    __hip_bfloat16* __restrict__ h0b,
    __hip_bfloat16* __restrict__ Yb, int N)
{
    __shared__ __align__(16) unsigned char lds[32768];   // GEMM1: 3x8KB stage; GEMM2: 64x512B h0 tile
    const int t = threadIdx.x;
    const int lane = t & 63;
    const int w = t >> 6;
    const int m0 = blockIdx.x * 64;
    const int g = lane >> 4;
    const int rl = lane & 15;

    // ---------------- GEMM1 (R8 structure, verbatim) ----------------
    auto stageA = [&](int ks, int buf) {
#pragma unroll
        for (int j = 0; j < 2; ++j) {
            int slot = j * 4 + w;
            int r = slot * 8 + (lane >> 3);
            int grow = m0 + r; if (grow >= N) grow = m0;
            int q = (lane & 7) ^ (lane >> 3);
            const float* src = (ks < 12)
                ? (ft + (size_t)grow * 384 + ks * 32 + q * 4)
                : (fi + (size_t)grow * 512 + (ks - 12) * 32 + q * 4);
            gld16(src, lds + buf * 8192 + slot * 1024);
        }
    };
    auto loadB1 = [&](short8 (&bf)[4], int ks) {
#pragma unroll
        for (int fc = 0; fc < 4; ++fc)
            bf[fc] = *(const short8*)((const short*)wp1 +
                      (size_t)(ks * 256 + w * 64 + fc * 16 + rl) * 32 + g * 8);
    };

    f32x4 acc[4][4];
#pragma unroll
    for (int i = 0; i < 4; ++i)
#pragma unroll
        for (int j = 0; j < 4; ++j) acc[i][j] = (f32x4){0.f, 0.f, 0.f, 0.f};

    auto compute1 = [&](int ks, short8 (&bf)[4]) {
        const unsigned char* Ab = lds + (ks % 3) * 8192;
        short8 af[4];
#pragma unroll
        for (int fr = 0; fr < 4; ++fr) {
            int r = fr * 16 + rl;
            const unsigned char* base = Ab + r * 128;
            f32x4 lo = *(const f32x4*)(base + ((2 * g) ^ (r & 7)) * 16);
            f32x4 hi = *(const f32x4*)(base + ((2 * g + 1) ^ (r & 7)) * 16);
            union { short8 s8; unsigned u[4]; } cv;
            cv.u[0] = bfpk(lo[0], lo[1]);
            cv.u[1] = bfpk(lo[2], lo[3]);
            cv.u[2] = bfpk(hi[0], hi[1]);
            cv.u[3] = bfpk(hi[2], hi[3]);
            af[fr] = cv.s8;
        }
#pragma unroll
        for (int fr = 0; fr < 4; ++fr)
#pragma unroll
            for (int fc = 0; fc < 4; ++fc)
                acc[fr][fc] = __builtin_amdgcn_mfma_f32_16x16x32_bf16(af[fr], bf[fc], acc[fr][fc], 0, 0, 0);
    };

    short8 bfe[4], bfo[4];
    stageA(0, 0);
    stageA(1, 1);
    loadB1(bfe, 0);

#pragma unroll 1
    for (int p = 0; p < 14; ++p) {
        const int ks = 2 * p;
        asm volatile("s_waitcnt vmcnt(6)" ::: "memory");
        __builtin_amdgcn_s_barrier();
        __builtin_amdgcn_sched_barrier(0);
        if (ks + 2 < 28) stageA(ks + 2, (ks + 2) % 3);
        loadB1(bfo, ks + 1);
        compute1(ks, bfe);
        if (p == 13) asm volatile("s_waitcnt vmcnt(0)" ::: "memory");
        else         asm volatile("s_waitcnt vmcnt(6)" ::: "memory");
        __builtin_amdgcn_s_barrier();
        __builtin_amdgcn_sched_barrier(0);
        if (ks + 3 < 28) stageA(ks + 3, (ks + 3) % 3);
        if (ks + 2 < 28) loadB1(bfe, ks + 2);
        compute1(ks + 1, bfo);
    }
    __syncthreads();   // all stage-buffer reads complete before overwrite

    // ------------- h0 -> LDS tile (swizzled) -------------
    // tile: row r (0..63) x 256 bf16; 16B chunk c stored at c ^ (r&31).
    const int cbase = w * 64;
#pragma unroll
    for (int fr = 0; fr < 4; ++fr)
#pragma unroll
        for (int reg = 0; reg < 4; ++reg) {
            int rloc = fr * 16 + g * 4 + reg;
            int grow = m0 + rloc;
#pragma unroll
            for (int fc = 0; fc < 4; ++fc) {
                float vv = acc[fr][fc][reg];
                if (grow == 0) vv = 0.f;
                int col = cbase + fc * 16 + rl;
                int phys = (col >> 3) ^ (rloc & 31);
                *(__hip_bfloat16*)(lds + rloc * 512 + phys * 16 + (col & 7) * 2) =
                    __float2bfloat16(vv);
            }
        }
    __syncthreads();

    // ------------- h0b global write (coalesced re-read of tile) -------------
#pragma unroll
    for (int j = 0; j < 8; ++j) {
        int ci = t + j * 256;            // 2048 16B-chunks
        int r = ci >> 5, c = ci & 31;
        int grow = m0 + r;
        if (grow < N) {
            short8 v = *(const short8*)(lds + r * 512 + ((c ^ (r & 31)) * 16));
            *(short8*)(h0b + (size_t)grow * 256 + c * 8) = v;
        }
    }

    // ------------- GEMM2: Y[rel] = h0 @ W_rel (no barriers) -------------
#pragma unroll 1
    for (int rel = 0; rel < 3; ++rel) {
        f32x4 acc2[4][4];
#pragma unroll
        for (int i = 0; i < 4; ++i)
#pragma unroll
            for (int j = 0; j < 4; ++j) acc2[i][j] = (f32x4){0.f, 0.f, 0.f, 0.f};

#pragma unroll
        for (int ks = 0; ks < 8; ++ks) {
            short8 af[4];
#pragma unroll
            for (int fr = 0; fr < 4; ++fr) {
                int r = fr * 16 + rl;
                int phys = (ks * 4 + g) ^ (r & 31);
                af[fr] = *(const short8*)(lds + r * 512 + phys * 16);
            }
            short8 bf[4];
#pragma unroll
            for (int fc = 0; fc < 4; ++fc)
                bf[fc] = *(const short8*)((const short*)wp2 +
                          (size_t)((rel * 8 + ks) * 256 + w * 64 + fc * 16 + rl) * 32 + g * 8);
#pragma unroll
            for (int fr = 0; fr < 4; ++fr)
#pragma unroll
                for (int fc = 0; fc < 4; ++fc)
                    acc2[fr][fc] = __builtin_amdgcn_mfma_f32_16x16x32_bf16(af[fr], bf[fc], acc2[fr][fc], 0, 0, 0);
        }
        __hip_bfloat16* Yr = Yb + (size_t)rel * N * 256;
#pragma unroll
        for (int fr = 0; fr < 4; ++fr)
#pragma unroll
            for (int reg = 0; reg < 4; ++reg) {
                int grow = m0 + fr * 16 + g * 4 + reg;
                if (grow >= N) continue;
#pragma unroll
                for (int fc = 0; fc < 4; ++fc)
                    Yr[(size_t)grow * 256 + cbase + fc * 16 + rl] =
                        __float2bfloat16(acc2[fr][fc][reg]);
            }
    }
}

// k2ln: one wave per dst node. Walk chain: acc[rel] += w * Y[rel][src] (bf16 gather),
// denom[rel] += w. Then x = h0b[d] + sum_rel acc/max(denom,eps); LayerNorm; out f32.
__global__ __launch_bounds__(512) void k2ln(
    const __hip_bfloat16* __restrict__ Yb,
    const __hip_bfloat16* __restrict__ h0b,
    const int* __restrict__ esrc, const int* __restrict__ etype,
    const float* __restrict__ ew,
    const int* __restrict__ head, const int* __restrict__ nxt,
    const float* __restrict__ gamma, const float* __restrict__ beta,
    float* __restrict__ out, int N)
{
    int w = threadIdx.x >> 6;
    int lane = threadIdx.x & 63;
    int d = blockIdx.x * 8 + w;
    if (d >= N) return;

    f32x4 a0 = {0.f, 0.f, 0.f, 0.f}, a1 = a0, a2 = a0;
    float d0 = 0.f, d1 = 0.f, d2 = 0.f;

    int e = head[d];
    while (e >= 0) {
        int src = esrc[e];
        int ty = etype[e];          // wave-uniform
        float we = ew[e];
        uint2 yv = *(const uint2*)(Yb + ((size_t)ty * N + src) * 256 + lane * 4);
        f32x4 y = bf4_to_f32(yv);
        if (ty == 0)      { a0 += we * y; d0 += we; }
        else if (ty == 1) { a1 += we * y; d1 += we; }
        else              { a2 += we * y; d2 += we; }
        e = nxt[e];
    }

    float i0 = 1.0f / fmaxf(d0, DENOM_EPS);
    float i1 = 1.0f / fmaxf(d1, DENOM_EPS);
    float i2 = 1.0f / fmaxf(d2, DENOM_EPS);

    f32x4 h = bf4_to_f32(*(const uint2*)(h0b + (size_t)d * 256 + lane * 4));
    f32x4 x;
#pragma unroll
    for (int j = 0; j < 4; ++j)
        x[j] = h[j] + a0[j] * i0 + a1[j] * i1 + a2[j] * i2;

    float s = x[0] + x[1] + x[2] + x[3];
    float q = x[0] * x[0] + x[1] * x[1] + x[2] * x[2] + x[3] * x[3];
#pragma unroll
    for (int off = 1; off < 64; off <<= 1) {
        s += __shfl_xor(s, off, 64);
        q += __shfl_xor(q, off, 64);
    }
    float mu  = s * (1.f / 256.f);
    float var = q * (1.f / 256.f) - mu * mu;
    float rstd = rsqrtf(var + LN_EPS);

    const float4 g4 = *(const float4*)(gamma + lane * 4);
    const float4 b4 = *(const float4*)(beta + lane * 4);
    float4 o;
    o.x = (x[0] - mu) * rstd * g4.x + b4.x;
    o.y = (x[1] - mu) * rstd * g4.y + b4.y;
    o.z = (x[2] - mu) * rstd * g4.z + b4.z;
    o.w = (x[3] - mu) * rstd * g4.w + b4.w;
    if (d == 0) o = make_float4(0.f, 0.f, 0.f, 0.f);
    *(float4*)(out + (size_t)d * 256 + lane * 4) = o;
}

extern "C" void kernel_launch(void* const* d_in, const int* in_sizes, int n_in,
                              void* d_out, int out_size, void* d_ws, size_t ws_size,
                              hipStream_t stream) {
    const int N = in_sizes[0] / 384;   // 100000
    const int E = in_sizes[7];         // 300000
    const float* ft    = (const float*)d_in[0];
    const float* fi    = (const float*)d_in[1];
    const float* wt    = (const float*)d_in[2];
    const float* wi    = (const float*)d_in[3];
    const float* wrel  = (const float*)d_in[4];
    const float* gamma = (const float*)d_in[5];
    const float* beta  = (const float*)d_in[6];
    const float* ew    = (const float*)d_in[7];
    const int*   eidx  = (const int*)d_in[8];
    const int*   etype = (const int*)d_in[9];
    float* out = (float*)d_out;

    // ws: Y bf16 [3][N][256] | h0b bf16 [N][256] | head int[N] | nxt int[E] | wp1 | wp2
    __hip_bfloat16* Yb  = (__hip_bfloat16*)d_ws;
    __hip_bfloat16* h0b = Yb + (size_t)3 * N * 256;
    int* head = (int*)(h0b + (size_t)N * 256);
    int* nxt  = head + N;
    __hip_bfloat16* wp1 = (__hip_bfloat16*)(nxt + E);
    __hip_bfloat16* wp2 = wp1 + WP1_ELEMS;

    hipMemsetAsync(head, 0xFF, (size_t)N * sizeof(int), stream);

    kpack<<<(WP1_ELEMS + WP2_ELEMS + 255) / 256, 256, 0, stream>>>(wt, wi, wrel, wp1, wp2);

    kchain<<<(E + 255) / 256, 256, 0, stream>>>(eidx + E, head, nxt, E);

    const int gblocks = (N + 63) / 64;                   // 1563
    kg0f<<<gblocks, 256, 0, stream>>>(ft, fi, wp1, wp2, h0b, Yb, N);

    k2ln<<<(N + 7) / 8, 512, 0, stream>>>(Yb, h0b, eidx, etype, ew, head, nxt,
                                          gamma, beta, out, N);
}

// Round 13
// 390.900 us; speedup vs baseline: 1.4938x; 1.0490x over previous
//
#include <hip/hip_runtime.h>
#include <hip/hip_bf16.h>

#define HID 256
#define LN_EPS 1e-5f
#define DENOM_EPS 1e-8f

typedef __attribute__((ext_vector_type(8))) short short8;
typedef __attribute__((ext_vector_type(4))) float f32x4;

#define WP1_ELEMS (28 * 256 * 32)   // K=896 packed (32k steps), pre-scaled by 0.5
#define WP2_ELEMS (24 * 256 * 32)   // K=768 (3 rels x 256)

__device__ inline unsigned bfpk(float x, float y) {
    __hip_bfloat162 h = __float22bfloat162_rn(make_float2(x, y));
    return *reinterpret_cast<unsigned*>(&h);
}

__device__ inline void gld16(const void* g, void* l) {
    __builtin_amdgcn_global_load_lds(
        (const __attribute__((address_space(1))) void*)g,
        (__attribute__((address_space(3))) void*)l, 16, 0, 0);
}

// Pack weights: wp[ks32][col][kk] = W[ks32*32+kk][col] (*0.5 for wp1)
__global__ __launch_bounds__(256) void kpack(
    const float* __restrict__ wt, const float* __restrict__ wi,
    const float* __restrict__ wrel,
    __hip_bfloat16* __restrict__ wp1, __hip_bfloat16* __restrict__ wp2)
{
    int idx = blockIdx.x * 256 + threadIdx.x;
    if (idx < WP1_ELEMS) {
        int kk = idx & 31, col = (idx >> 5) & 255, ks = idx >> 13;
        int k = ks * 32 + kk;
        float v = (k < 384) ? wt[k * 256 + col] : wi[(k - 384) * 256 + col];
        wp1[idx] = __float2bfloat16(v * 0.5f);
    } else {
        int j = idx - WP1_ELEMS;
        if (j < WP2_ELEMS) {
            int kk = j & 31, col = (j >> 5) & 255, ks = j >> 13;
            int k = ks * 32 + kk;
            wp2[j] = __float2bfloat16(wrel[k * 256 + col]);
        }
    }
}

__global__ __launch_bounds__(256) void kchain(
    const int* __restrict__ edst, int* __restrict__ head, int* __restrict__ nxt, int E)
{
    int e = blockIdx.x * 256 + threadIdx.x;
    if (e < E) nxt[e] = atomicExch(&head[edst[e]], e);
}

// One wave per dst node: walk chain, acc[rel] += w*h0[src];
// S[d][rel*256+c] = bf16(acc[rel][c] / max(denom[rel], eps)).  Row-major [N][768].
__global__ __launch_bounds__(512) void k2_gather(
    const float* __restrict__ h0, const int* __restrict__ esrc,
    const int* __restrict__ etype, const float* __restrict__ ew,
    const int* __restrict__ head, const int* __restrict__ nxt,
    __hip_bfloat16* __restrict__ S, int N)
{
    int w = threadIdx.x >> 6;
    int lane = threadIdx.x & 63;
    int d = blockIdx.x * 8 + w;
    if (d >= N) return;

    f32x4 a0 = {0.f, 0.f, 0.f, 0.f}, a1 = a0, a2 = a0;
    float d0 = 0.f, d1 = 0.f, d2 = 0.f;

    int e = head[d];
    while (e >= 0) {
        int src = esrc[e];
        int ty = etype[e];
        float w_ = ew[e];
        const float4 h = *(const float4*)(h0 + (size_t)src * HID + lane * 4);
        f32x4 hw = {w_ * h.x, w_ * h.y, w_ * h.z, w_ * h.w};
        if (ty == 0)      { a0 += hw; d0 += w_; }
        else if (ty == 1) { a1 += hw; d1 += w_; }
        else              { a2 += hw; d2 += w_; }
        e = nxt[e];
    }

    float i0 = 1.0f / fmaxf(d0, DENOM_EPS);
    float i1 = 1.0f / fmaxf(d1, DENOM_EPS);
    float i2 = 1.0f / fmaxf(d2, DENOM_EPS);
    __hip_bfloat16* row = S + (size_t)d * 768;
    uint2 p;
    p = make_uint2(bfpk(a0[0] * i0, a0[1] * i0), bfpk(a0[2] * i0, a0[3] * i0));
    *(uint2*)(row + 0   + lane * 4) = p;
    p = make_uint2(bfpk(a1[0] * i1, a1[1] * i1), bfpk(a1[2] * i1, a1[3] * i1));
    *(uint2*)(row + 256 + lane * 4) = p;
    p = make_uint2(bfpk(a2[0] * i2, a2[1] * i2), bfpk(a2[2] * i2, a2[3] * i2));
    *(uint2*)(row + 512 + lane * 4) = p;
}

// kg0: h0 = ft@wp1a + fi@wp1b (0.5 pre-folded), row 0 zeroed.
// 256x256 block tile, 512 thr, 8 waves (2M x 4N), wave tile 128x64, acc[8][4].
// BK=32, NT=28 tiles. A (f32) staged via global_load_lds TWO tiles ahead into
// 3 LDS buffers (32KB each); B = 4 reg-loads from L2-resident wp1, ONE tile
// ahead (named ping-pong sets). ONE barrier + counted vmcnt per tile: at tile t,
// loads younger than B(t) are exactly A(t+1)p2 (2) -> vmcnt(2) guarantees
// A(t)+B(t) complete while A(t+1)/A(t+2)/B(t+1) stay in flight.
// A LDS layout: row r (0..255) x 8 chunks of 16B; data chunk cc stored at
// phys cc^(r&7) (both-sides swizzle via pre-swizzled global source, rule #21).
__global__ __launch_bounds__(512, 2) void kg0(
    const float* __restrict__ ft, const float* __restrict__ fi,
    const __hip_bfloat16* __restrict__ wp,
    float* __restrict__ out, int N)
{
    constexpr int NT = 28;
    __shared__ __align__(16) unsigned char A3[3][32768];
    const int t = threadIdx.x;
    const int lane = t & 63;
    const int w = t >> 6;
    const int wr = w >> 2, wc = w & 3;
    const int m0 = blockIdx.x * 256;
    const int g = lane >> 4;
    const int rl = lane & 15;

    auto stageA = [&](int kt, int buf, int j) {
        int p = j * 512 + t;
        int r = p >> 3, cp = p & 7;
        int cc = cp ^ (r & 7);                       // data chunk for this phys slot
        int grow = m0 + r; if (grow >= N) grow = m0;
        const float* src = (kt < 12)
            ? ft + (size_t)grow * 384 + kt * 32 + cc * 4
            : fi + (size_t)grow * 512 + (kt - 12) * 32 + cc * 4;
        gld16(src, A3[buf] + (j * 512 + w * 64) * 16);   // uniform base + lane*16
    };
    auto loadB = [&](short8 (&bf)[4], int kt) {
#pragma unroll
        for (int fc = 0; fc < 4; ++fc)
            bf[fc] = *(const short8*)((const short*)wp +
                      (size_t)(kt * 256 + wc * 64 + fc * 16 + rl) * 32 + g * 8);
    };

    f32x4 acc[8][4];
#pragma unroll
    for (int i = 0; i < 8; ++i)
#pragma unroll
        for (int j = 0; j < 4; ++j) acc[i][j] = (f32x4){0.f, 0.f, 0.f, 0.f};

    auto half = [&](int kt, int h, short8 (&bfc)[4]) {   // h=0: fr 0..3, h=1: fr 4..7
        const unsigned char* Ab = A3[kt % 3];
        short8 af[4];
#pragma unroll
        for (int i = 0; i < 4; ++i) {
            int r = wr * 128 + (h * 4 + i) * 16 + rl;
            int c0 = (2 * g) ^ (r & 7);
            int c1 = (2 * g + 1) ^ (r & 7);
            f32x4 lo = *(const f32x4*)(Ab + r * 128 + c0 * 16);
            f32x4 hi = *(const f32x4*)(Ab + r * 128 + c1 * 16);
            union { short8 s8; unsigned u[4]; } cv;
            cv.u[0] = bfpk(lo[0], lo[1]);
            cv.u[1] = bfpk(lo[2], lo[3]);
            cv.u[2] = bfpk(hi[0], hi[1]);
            cv.u[3] = bfpk(hi[2], hi[3]);
            af[i] = cv.s8;
        }
        __builtin_amdgcn_s_setprio(1);
#pragma unroll
        for (int i = 0; i < 4; ++i)
#pragma unroll
            for (int fc = 0; fc < 4; ++fc)
                acc[h * 4 + i][fc] = __builtin_amdgcn_mfma_f32_16x16x32_bf16(
                    af[i], bfc[fc], acc[h * 4 + i][fc], 0, 0, 0);
        __builtin_amdgcn_s_setprio(0);
    };

    auto tile = [&](int kt, short8 (&bfc)[4], short8 (&bfn)[4]) {
        // tile-boundary wait: A(t)+B(t) complete; keep A(t+1)/A(t+2)/B(t+1) in flight
        if (kt == 0)           asm volatile("s_waitcnt vmcnt(4)" ::: "memory");
        else if (kt == NT - 1) asm volatile("s_waitcnt vmcnt(0)" ::: "memory");
        else                   asm volatile("s_waitcnt vmcnt(2)" ::: "memory");
        __builtin_amdgcn_s_barrier();
        __builtin_amdgcn_sched_barrier(0);
        int nb = (kt + 2) % 3;
        if (kt + 2 < NT) { stageA(kt + 2, nb, 0); stageA(kt + 2, nb, 1); }
        if (kt + 1 < NT) loadB(bfn, kt + 1);
        half(kt, 0, bfc);
        if (kt + 2 < NT) { stageA(kt + 2, nb, 2); stageA(kt + 2, nb, 3); }
        half(kt, 1, bfc);
    };

    short8 bfe[4], bfo[4];
    // prologue: A(0), B(0), A(1)  (order matters for tile-0 vmcnt(4))
#pragma unroll
    for (int j = 0; j < 4; ++j) stageA(0, 0, j);
    loadB(bfe, 0);
#pragma unroll
    for (int j = 0; j < 4; ++j) stageA(1, 1, j);

#pragma unroll 1
    for (int tp = 0; tp < NT / 2; ++tp) {
        tile(2 * tp, bfe, bfo);
        tile(2 * tp + 1, bfo, bfe);
    }

    // epilogue: C-write
#pragma unroll
    for (int fr = 0; fr < 8; ++fr)
#pragma unroll
        for (int reg = 0; reg < 4; ++reg) {
            int grow = m0 + wr * 128 + fr * 16 + g * 4 + reg;
            if (grow >= N) continue;
#pragma unroll
            for (int fc = 0; fc < 4; ++fc) {
                float vv = acc[fr][fc][reg];
                if (grow == 0) vv = 0.f;
                out[(size_t)grow * 256 + wc * 64 + fc * 16 + rl] = vv;
            }
        }
}

// kg1: out = LN(h0 + S@wp2), row 0 zeroed. h0in aliases out.
// Same 256-row schedule; A = S bf16 [N][768], NT=24, A tile 16KB (2 loads/thr),
// LDS data chunk g at phys g^((r>>1)&3). vmcnt: tile0=2, mid=1, last=0.
__global__ __launch_bounds__(512, 2) void kg1(
    const __hip_bfloat16* __restrict__ Sb,
    const __hip_bfloat16* __restrict__ wp,
    const float* h0in, const float* __restrict__ gamma,
    const float* __restrict__ beta, float* __restrict__ out, int N)
{
    constexpr int NT = 24;
    __shared__ __align__(16) unsigned char A3[3][16384];
    __shared__ float redS[256][4];
    __shared__ float redQ[256][4];

    const int t = threadIdx.x;
    const int lane = t & 63;
    const int w = t >> 6;
    const int wr = w >> 2, wc = w & 3;
    const int m0 = blockIdx.x * 256;
    const int g = lane >> 4;
    const int rl = lane & 15;

    auto stageA = [&](int kt, int buf, int j) {
        int p = j * 512 + t;
        int r = p >> 2, gp = p & 3;
        int gg = gp ^ ((r >> 1) & 3);
        int grow = m0 + r; if (grow >= N) grow = m0;
        const __hip_bfloat16* src = Sb + (size_t)grow * 768 + kt * 32 + gg * 8;
        gld16(src, A3[buf] + (j * 512 + w * 64) * 16);
    };
    auto loadB = [&](short8 (&bf)[4], int kt) {
#pragma unroll
        for (int fc = 0; fc < 4; ++fc)
            bf[fc] = *(const short8*)((const short*)wp +
                      (size_t)(kt * 256 + wc * 64 + fc * 16 + rl) * 32 + g * 8);
    };

    f32x4 acc[8][4];
#pragma unroll
    for (int i = 0; i < 8; ++i)
#pragma unroll
        for (int j = 0; j < 4; ++j) acc[i][j] = (f32x4){0.f, 0.f, 0.f, 0.f};

    auto half = [&](int kt, int h, short8 (&bfc)[4]) {
        const unsigned char* Ab = A3[kt % 3];
        short8 af[4];
#pragma unroll
        for (int i = 0; i < 4; ++i) {
            int r = wr * 128 + (h * 4 + i) * 16 + rl;
            int gph = g ^ ((r >> 1) & 3);
            af[i] = *(const short8*)(Ab + r * 64 + gph * 16);
        }
        __builtin_amdgcn_s_setprio(1);
#pragma unroll
        for (int i = 0; i < 4; ++i)
#pragma unroll
            for (int fc = 0; fc < 4; ++fc)
                acc[h * 4 + i][fc] = __builtin_amdgcn_mfma_f32_16x16x32_bf16(
                    af[i], bfc[fc], acc[h * 4 + i][fc], 0, 0, 0);
        __builtin_amdgcn_s_setprio(0);
    };

    auto tile = [&](int kt, short8 (&bfc)[4], short8 (&bfn)[4]) {
        if (kt == 0)           asm volatile("s_waitcnt vmcnt(2)" ::: "memory");
        else if (kt == NT - 1) asm volatile("s_waitcnt vmcnt(0)" ::: "memory");
        else                   asm volatile("s_waitcnt vmcnt(1)" ::: "memory");
        __builtin_amdgcn_s_barrier();
        __builtin_amdgcn_sched_barrier(0);
        int nb = (kt + 2) % 3;
        if (kt + 2 < NT) stageA(kt + 2, nb, 0);
        if (kt + 1 < NT) loadB(bfn, kt + 1);
        half(kt, 0, bfc);
        if (kt + 2 < NT) stageA(kt + 2, nb, 1);
        half(kt, 1, bfc);
    };

    short8 bfe[4], bfo[4];
    stageA(0, 0, 0); stageA(0, 0, 1);
    loadB(bfe, 0);
    stageA(1, 1, 0); stageA(1, 1, 1);

#pragma unroll 1
    for (int tp = 0; tp < NT / 2; ++tp) {
        tile(2 * tp, bfe, bfo);
        tile(2 * tp + 1, bfo, bfe);
    }

    // epilogue: residual + LN
#pragma unroll
    for (int fr = 0; fr < 8; ++fr)
#pragma unroll
        for (int reg = 0; reg < 4; ++reg) {
            int grow = m0 + wr * 128 + fr * 16 + g * 4 + reg;
            if (grow < N) {
#pragma unroll
                for (int fc = 0; fc < 4; ++fc)
                    acc[fr][fc][reg] += h0in[(size_t)grow * 256 + wc * 64 + fc * 16 + rl];
            }
        }
#pragma unroll
    for (int fr = 0; fr < 8; ++fr)
#pragma unroll
        for (int reg = 0; reg < 4; ++reg) {
            float s = 0.f, q = 0.f;
#pragma unroll
            for (int fc = 0; fc < 4; ++fc) {
                float vv = acc[fr][fc][reg];
                s += vv; q += vv * vv;
            }
#pragma unroll
            for (int off = 1; off < 16; off <<= 1) {
                s += __shfl_xor(s, off, 64);
                q += __shfl_xor(q, off, 64);
            }
            if (rl == 0) {
                int rli = wr * 128 + fr * 16 + g * 4 + reg;
                redS[rli][wc] = s;
                redQ[rli][wc] = q;
            }
        }
    __syncthreads();
    float g4[4], b4[4];
#pragma unroll
    for (int fc = 0; fc < 4; ++fc) {
        g4[fc] = gamma[wc * 64 + fc * 16 + rl];
        b4[fc] = beta[wc * 64 + fc * 16 + rl];
    }
#pragma unroll
    for (int fr = 0; fr < 8; ++fr)
#pragma unroll
        for (int reg = 0; reg < 4; ++reg) {
            int rli = wr * 128 + fr * 16 + g * 4 + reg;
            int grow = m0 + rli;
            if (grow >= N) continue;
            float s = redS[rli][0] + redS[rli][1] + redS[rli][2] + redS[rli][3];
            float q = redQ[rli][0] + redQ[rli][1] + redQ[rli][2] + redQ[rli][3];
            float mu  = s * (1.f / 256.f);
            float var = q * (1.f / 256.f) - mu * mu;
            float rstd = rsqrtf(var + LN_EPS);
#pragma unroll
            for (int fc = 0; fc < 4; ++fc) {
                float vv = (acc[fr][fc][reg] - mu) * rstd * g4[fc] + b4[fc];
                if (grow == 0) vv = 0.f;
                out[(size_t)grow * 256 + wc * 64 + fc * 16 + rl] = vv;
            }
        }
}

extern "C" void kernel_launch(void* const* d_in, const int* in_sizes, int n_in,
                              void* d_out, int out_size, void* d_ws, size_t ws_size,
                              hipStream_t stream) {
    const int N = in_sizes[0] / 384;   // 100000
    const int E = in_sizes[7];         // 300000
    const float* ft    = (const float*)d_in[0];
    const float* fi    = (const float*)d_in[1];
    const float* wt    = (const float*)d_in[2];
    const float* wi    = (const float*)d_in[3];
    const float* wrel  = (const float*)d_in[4];
    const float* gamma = (const float*)d_in[5];
    const float* beta  = (const float*)d_in[6];
    const float* ew    = (const float*)d_in[7];
    const int*   eidx  = (const int*)d_in[8];
    const int*   etype = (const int*)d_in[9];
    float* out = (float*)d_out;

    // ws layout: S bf16 [N][768] | head int[N] | next int[E] | wp1 | wp2
    __hip_bfloat16* S = (__hip_bfloat16*)d_ws;
    int* head = (int*)((char*)d_ws + (size_t)N * 768 * 2);
    int* nxt  = head + N;
    __hip_bfloat16* wp1 = (__hip_bfloat16*)(nxt + E);
    __hip_bfloat16* wp2 = wp1 + WP1_ELEMS;

    hipMemsetAsync(head, 0xFF, (size_t)N * sizeof(int), stream);

    kpack<<<(WP1_ELEMS + WP2_ELEMS + 255) / 256, 256, 0, stream>>>(wt, wi, wrel, wp1, wp2);

    kchain<<<(E + 255) / 256, 256, 0, stream>>>(eidx + E, head, nxt, E);

    const int gblocks = (N + 255) / 256;                 // 391
    kg0<<<gblocks, 512, 0, stream>>>(ft, fi, wp1, out, N);

    k2_gather<<<(N + 7) / 8, 512, 0, stream>>>(out, eidx, etype, ew, head, nxt, S, N);

    kg1<<<gblocks, 512, 0, stream>>>(S, wp2, out, gamma, beta, out, N);
}

// Round 14
// 382.572 us; speedup vs baseline: 1.5263x; 1.0218x over previous
//
#include <hip/hip_runtime.h>
#include <hip/hip_bf16.h>

#define HID 256
#define LN_EPS 1e-5f
#define DENOM_EPS 1e-8f

typedef __attribute__((ext_vector_type(8))) short short8;
typedef __attribute__((ext_vector_type(4))) float f32x4;

#define WP1_ELEMS (28 * 256 * 32)   // K=896 packed, pre-scaled by 0.5
#define WP2_ELEMS (24 * 256 * 32)   // K=768 (3 rels x 256)

__device__ inline unsigned bfpk(float x, float y) {
    __hip_bfloat162 h = __float22bfloat162_rn(make_float2(x, y));
    return *reinterpret_cast<unsigned*>(&h);
}

__device__ inline void gld16(const void* g, void* l) {
    __builtin_amdgcn_global_load_lds(
        (const __attribute__((address_space(1))) void*)g,
        (__attribute__((address_space(3))) void*)l, 16, 0, 0);
}

__device__ inline f32x4 bf4_to_f32(uint2 p) {
    union { float f; unsigned u; } c;
    f32x4 r;
    c.u = (p.x & 0xFFFFu) << 16;  r[0] = c.f;
    c.u = (p.x & 0xFFFF0000u);    r[1] = c.f;
    c.u = (p.y & 0xFFFFu) << 16;  r[2] = c.f;
    c.u = (p.y & 0xFFFF0000u);    r[3] = c.f;
    return r;
}

// bijective XCD swizzle (m204): consecutive logical blocks land on one XCD
__device__ inline int xcd_swz(int b, int nwg) {
    int q = nwg >> 3, r = nwg & 7;
    int xcd = b & 7, idx = b >> 3;
    return (xcd < r) ? (xcd * (q + 1) + idx) : (r * (q + 1) + (xcd - r) * q + idx);
}

// Pack weights: wp[ks32][col][kk] = W[ks32*32+kk][col] (*0.5 for wp1)
__global__ __launch_bounds__(256) void kpack(
    const float* __restrict__ wt, const float* __restrict__ wi,
    const float* __restrict__ wrel,
    __hip_bfloat16* __restrict__ wp1, __hip_bfloat16* __restrict__ wp2)
{
    int idx = blockIdx.x * 256 + threadIdx.x;
    if (idx < WP1_ELEMS) {
        int kk = idx & 31, col = (idx >> 5) & 255, ks = idx >> 13;
        int k = ks * 32 + kk;
        float v = (k < 384) ? wt[k * 256 + col] : wi[(k - 384) * 256 + col];
        wp1[idx] = __float2bfloat16(v * 0.5f);
    } else {
        int j = idx - WP1_ELEMS;
        if (j < WP2_ELEMS) {
            int kk = j & 31, col = (j >> 5) & 255, ks = j >> 13;
            int k = ks * 32 + kk;
            wp2[j] = __float2bfloat16(wrel[k * 256 + col]);
        }
    }
}

__global__ __launch_bounds__(256) void kchain(
    const int* __restrict__ edst, int* __restrict__ head, int* __restrict__ nxt, int E)
{
    int e = blockIdx.x * 256 + threadIdx.x;
    if (e < E) nxt[e] = atomicExch(&head[edst[e]], e);
}

// k2: 8 waves/block, one dst node per wave. Gathers BF16 h0 rows (512B/edge).
// S[d][rel*256+c] = bf16(acc[rel][c] / max(denom[rel], eps)), row-major [N][768].
__global__ __launch_bounds__(512) void k2_gather(
    const __hip_bfloat16* __restrict__ h0b, const int* __restrict__ esrc,
    const int* __restrict__ etype, const float* __restrict__ ew,
    const int* __restrict__ head, const int* __restrict__ nxt,
    __hip_bfloat16* __restrict__ S, int N)
{
    int w = threadIdx.x >> 6;
    int lane = threadIdx.x & 63;
    int d = blockIdx.x * 8 + w;
    if (d >= N) return;

    f32x4 a0 = {0.f, 0.f, 0.f, 0.f}, a1 = a0, a2 = a0;
    float d0 = 0.f, d1 = 0.f, d2 = 0.f;

    int e = head[d];
    while (e >= 0) {
        int src = esrc[e];
        int ty = etype[e];          // wave-uniform
        float we = ew[e];
        uint2 hv = *(const uint2*)(h0b + (size_t)src * HID + lane * 4);
        f32x4 h = bf4_to_f32(hv);
        if (ty == 0)      { a0 += we * h; d0 += we; }
        else if (ty == 1) { a1 += we * h; d1 += we; }
        else              { a2 += we * h; d2 += we; }
        e = nxt[e];
    }

    float i0 = 1.0f / fmaxf(d0, DENOM_EPS);
    float i1 = 1.0f / fmaxf(d1, DENOM_EPS);
    float i2 = 1.0f / fmaxf(d2, DENOM_EPS);
    __hip_bfloat16* row = S + (size_t)d * 768;
    uint2 p;
    p = make_uint2(bfpk(a0[0] * i0, a0[1] * i0), bfpk(a0[2] * i0, a0[3] * i0));
    *(uint2*)(row + 0   + lane * 4) = p;
    p = make_uint2(bfpk(a1[0] * i1, a1[1] * i1), bfpk(a1[2] * i1, a1[3] * i1));
    *(uint2*)(row + 256 + lane * 4) = p;
    p = make_uint2(bfpk(a2[0] * i2, a2[1] * i2), bfpk(a2[2] * i2, a2[3] * i2));
    *(uint2*)(row + 512 + lane * 4) = p;
}

// kg0: h0b = bf16(ft@wp1a + fi@wp1b) (0.5 pre-folded), row 0 zeroed.
// R8 structure verbatim: 64x256 tile, 4 waves, counted-vmcnt pair-unrolled loop,
// 3 LDS buffers, global_load_lds, both-sides swizzle. + XCD swizzle on blockIdx.
__global__ __launch_bounds__(256, 4) void kg0(
    const float* __restrict__ ft, const float* __restrict__ fi,
    const __hip_bfloat16* __restrict__ wp,
    __hip_bfloat16* __restrict__ h0b, int N, int nwg)
{
    constexpr int NSTEPS = 28;
    __shared__ __align__(16) unsigned char As[3][8192];

    const int t = threadIdx.x;
    const int lane = t & 63;
    const int w = t >> 6;
    const int m0 = xcd_swz(blockIdx.x, nwg) * 64;
    const int g = lane >> 4;
    const int rl = lane & 15;

    auto stageA = [&](int ks, int buf) {
#pragma unroll
        for (int j = 0; j < 2; ++j) {
            int slot = j * 4 + w;
            int r = slot * 8 + (lane >> 3);
            int grow = m0 + r; if (grow >= N) grow = m0;
            int q = (lane & 7) ^ (lane >> 3);
            const float* src = (ks < 12)
                ? (ft + (size_t)grow * 384 + ks * 32 + q * 4)
                : (fi + (size_t)grow * 512 + (ks - 12) * 32 + q * 4);
            gld16(src, As[buf] + slot * 1024);
        }
    };
    auto loadB = [&](short8 (&bf)[4], int ks) {
#pragma unroll
        for (int fc = 0; fc < 4; ++fc)
            bf[fc] = *(const short8*)((const short*)wp +
                      (size_t)(ks * 256 + w * 64 + fc * 16 + rl) * 32 + g * 8);
    };

    f32x4 acc[4][4];
#pragma unroll
    for (int i = 0; i < 4; ++i)
#pragma unroll
        for (int j = 0; j < 4; ++j) acc[i][j] = (f32x4){0.f, 0.f, 0.f, 0.f};

    auto compute = [&](int ks, short8 (&bf)[4]) {
        const unsigned char* Ab = As[ks % 3];
        short8 af[4];
#pragma unroll
        for (int fr = 0; fr < 4; ++fr) {
            int r = fr * 16 + rl;
            const unsigned char* base = Ab + r * 128;
            f32x4 lo = *(const f32x4*)(base + ((2 * g) ^ (r & 7)) * 16);
            f32x4 hi = *(const f32x4*)(base + ((2 * g + 1) ^ (r & 7)) * 16);
            union { short8 s8; unsigned u[4]; } cv;
            cv.u[0] = bfpk(lo[0], lo[1]);
            cv.u[1] = bfpk(lo[2], lo[3]);
            cv.u[2] = bfpk(hi[0], hi[1]);
            cv.u[3] = bfpk(hi[2], hi[3]);
            af[fr] = cv.s8;
        }
#pragma unroll
        for (int fr = 0; fr < 4; ++fr)
#pragma unroll
            for (int fc = 0; fc < 4; ++fc)
                acc[fr][fc] = __builtin_amdgcn_mfma_f32_16x16x32_bf16(af[fr], bf[fc], acc[fr][fc], 0, 0, 0);
    };

    short8 bfe[4], bfo[4];
    stageA(0, 0);
    stageA(1, 1);
    loadB(bfe, 0);

    constexpr int NP = NSTEPS / 2;
#pragma unroll 1
    for (int p = 0; p < NP; ++p) {
        const int ks = 2 * p;
        asm volatile("s_waitcnt vmcnt(6)" ::: "memory");
        __builtin_amdgcn_s_barrier();
        __builtin_amdgcn_sched_barrier(0);
        if (ks + 2 < NSTEPS) stageA(ks + 2, (ks + 2) % 3);
        loadB(bfo, ks + 1);
        compute(ks, bfe);
        if (p == NP - 1) asm volatile("s_waitcnt vmcnt(0)" ::: "memory");
        else             asm volatile("s_waitcnt vmcnt(6)" ::: "memory");
        __builtin_amdgcn_s_barrier();
        __builtin_amdgcn_sched_barrier(0);
        if (ks + 3 < NSTEPS) stageA(ks + 3, (ks + 3) % 3);
        if (ks + 2 < NSTEPS) loadB(bfe, ks + 2);
        compute(ks + 1, bfo);
    }

    const int cbase = w * 64;
#pragma unroll
    for (int fr = 0; fr < 4; ++fr)
#pragma unroll
        for (int reg = 0; reg < 4; ++reg) {
            int grow = m0 + fr * 16 + g * 4 + reg;
            if (grow >= N) continue;
#pragma unroll
            for (int fc = 0; fc < 4; ++fc) {
                float vv = acc[fr][fc][reg];
                if (grow == 0) vv = 0.f;
                h0b[(size_t)grow * 256 + cbase + fc * 16 + rl] = __float2bfloat16(vv);
            }
        }
}

// kg1: out = LN(h0b + S@wp2), row 0 zeroed. A = S bf16 [N][768], R8 structure.
__global__ __launch_bounds__(256, 4) void kg1(
    const __hip_bfloat16* __restrict__ Sb,
    const __hip_bfloat16* __restrict__ wp,
    const __hip_bfloat16* __restrict__ h0b,
    const float* __restrict__ gamma, const float* __restrict__ beta,
    float* __restrict__ out, int N, int nwg)
{
    constexpr int NSTEPS = 24;
    __shared__ __align__(16) unsigned char As[3][4096];
    __shared__ float redS[64][4];
    __shared__ float redQ[64][4];

    const int t = threadIdx.x;
    const int lane = t & 63;
    const int w = t >> 6;
    const int m0 = xcd_swz(blockIdx.x, nwg) * 64;
    const int g = lane >> 4;
    const int rl = lane & 15;

    auto stageA = [&](int ks, int buf) {
        int r = w * 16 + (lane >> 2);
        int grow = m0 + r; if (grow >= N) grow = m0;
        int q = (lane & 3) ^ ((lane >> 3) & 3);
        const __hip_bfloat16* src = Sb + (size_t)grow * 768 + ks * 32 + q * 8;
        gld16(src, As[buf] + w * 1024);
    };
    auto loadB = [&](short8 (&bf)[4], int ks) {
#pragma unroll
        for (int fc = 0; fc < 4; ++fc)
            bf[fc] = *(const short8*)((const short*)wp +
                      (size_t)(ks * 256 + w * 64 + fc * 16 + rl) * 32 + g * 8);
    };

    f32x4 acc[4][4];
#pragma unroll
    for (int i = 0; i < 4; ++i)
#pragma unroll
        for (int j = 0; j < 4; ++j) acc[i][j] = (f32x4){0.f, 0.f, 0.f, 0.f};

    auto compute = [&](int ks, short8 (&bf)[4]) {
        const unsigned char* Ab = As[ks % 3];
        short8 af[4];
#pragma unroll
        for (int fr = 0; fr < 4; ++fr) {
            int r = fr * 16 + rl;
            af[fr] = *(const short8*)(Ab + r * 64 + (g ^ ((r >> 1) & 3)) * 16);
        }
#pragma unroll
        for (int fr = 0; fr < 4; ++fr)
#pragma unroll
            for (int fc = 0; fc < 4; ++fc)
                acc[fr][fc] = __builtin_amdgcn_mfma_f32_16x16x32_bf16(af[fr], bf[fc], acc[fr][fc], 0, 0, 0);
    };

    short8 bfe[4], bfo[4];
    stageA(0, 0);
    stageA(1, 1);
    loadB(bfe, 0);

    constexpr int NP = NSTEPS / 2;
#pragma unroll 1
    for (int p = 0; p < NP; ++p) {
        const int ks = 2 * p;
        asm volatile("s_waitcnt vmcnt(5)" ::: "memory");
        __builtin_amdgcn_s_barrier();
        __builtin_amdgcn_sched_barrier(0);
        if (ks + 2 < NSTEPS) stageA(ks + 2, (ks + 2) % 3);
        loadB(bfo, ks + 1);
        compute(ks, bfe);
        if (p == NP - 1) asm volatile("s_waitcnt vmcnt(0)" ::: "memory");
        else             asm volatile("s_waitcnt vmcnt(5)" ::: "memory");
        __builtin_amdgcn_s_barrier();
        __builtin_amdgcn_sched_barrier(0);
        if (ks + 3 < NSTEPS) stageA(ks + 3, (ks + 3) % 3);
        if (ks + 2 < NSTEPS) loadB(bfe, ks + 2);
        compute(ks + 1, bfo);
    }

    const int cbase = w * 64;
    // residual from bf16 h0
#pragma unroll
    for (int fr = 0; fr < 4; ++fr)
#pragma unroll
        for (int reg = 0; reg < 4; ++reg) {
            int grow = m0 + fr * 16 + g * 4 + reg;
            if (grow < N) {
#pragma unroll
                for (int fc = 0; fc < 4; ++fc)
                    acc[fr][fc][reg] +=
                        __bfloat162float(h0b[(size_t)grow * 256 + cbase + fc * 16 + rl]);
            }
        }
#pragma unroll
    for (int fr = 0; fr < 4; ++fr)
#pragma unroll
        for (int reg = 0; reg < 4; ++reg) {
            float s = 0.f, q = 0.f;
#pragma unroll
            for (int fc = 0; fc < 4; ++fc) {
                float vv = acc[fr][fc][reg];
                s += vv; q += vv * vv;
            }
#pragma unroll
            for (int off = 1; off < 16; off <<= 1) {
                s += __shfl_xor(s, off, 64);
                q += __shfl_xor(q, off, 64);
            }
            if (rl == 0) {
                int rli = fr * 16 + g * 4 + reg;
                redS[rli][w] = s;
                redQ[rli][w] = q;
            }
        }
    __syncthreads();
    float g4[4], b4[4];
#pragma unroll
    for (int fc = 0; fc < 4; ++fc) {
        g4[fc] = gamma[cbase + fc * 16 + rl];
        b4[fc] = beta[cbase + fc * 16 + rl];
    }
#pragma unroll
    for (int fr = 0; fr < 4; ++fr)
#pragma unroll
        for (int reg = 0; reg < 4; ++reg) {
            int rli = fr * 16 + g * 4 + reg;
            int grow = m0 + rli;
            if (grow >= N) continue;
            float s = redS[rli][0] + redS[rli][1] + redS[rli][2] + redS[rli][3];
            float q = redQ[rli][0] + redQ[rli][1] + redQ[rli][2] + redQ[rli][3];
            float mu  = s * (1.f / 256.f);
            float var = q * (1.f / 256.f) - mu * mu;
            float rstd = rsqrtf(var + LN_EPS);
#pragma unroll
            for (int fc = 0; fc < 4; ++fc) {
                float vv = (acc[fr][fc][reg] - mu) * rstd * g4[fc] + b4[fc];
                if (grow == 0) vv = 0.f;
                out[(size_t)grow * 256 + cbase + fc * 16 + rl] = vv;
            }
        }
}

extern "C" void kernel_launch(void* const* d_in, const int* in_sizes, int n_in,
                              void* d_out, int out_size, void* d_ws, size_t ws_size,
                              hipStream_t stream) {
    const int N = in_sizes[0] / 384;   // 100000
    const int E = in_sizes[7];         // 300000
    const float* ft    = (const float*)d_in[0];
    const float* fi    = (const float*)d_in[1];
    const float* wt    = (const float*)d_in[2];
    const float* wi    = (const float*)d_in[3];
    const float* wrel  = (const float*)d_in[4];
    const float* gamma = (const float*)d_in[5];
    const float* beta  = (const float*)d_in[6];
    const float* ew    = (const float*)d_in[7];
    const int*   eidx  = (const int*)d_in[8];
    const int*   etype = (const int*)d_in[9];
    float* out = (float*)d_out;

    // ws: S bf16 [N][768] | h0b bf16 [N][256] | head int[N] | nxt int[E] | wp1 | wp2
    __hip_bfloat16* S   = (__hip_bfloat16*)d_ws;
    __hip_bfloat16* h0b = S + (size_t)N * 768;
    int* head = (int*)(h0b + (size_t)N * 256);
    int* nxt  = head + N;
    __hip_bfloat16* wp1 = (__hip_bfloat16*)(nxt + E);
    __hip_bfloat16* wp2 = wp1 + WP1_ELEMS;

    hipMemsetAsync(head, 0xFF, (size_t)N * sizeof(int), stream);

    kpack<<<(WP1_ELEMS + WP2_ELEMS + 255) / 256, 256, 0, stream>>>(wt, wi, wrel, wp1, wp2);

    kchain<<<(E + 255) / 256, 256, 0, stream>>>(eidx + E, head, nxt, E);

    const int gblocks = (N + 63) / 64;                   // 1563
    kg0<<<gblocks, 256, 0, stream>>>(ft, fi, wp1, h0b, N, gblocks);

    k2_gather<<<(N + 7) / 8, 512, 0, stream>>>(h0b, eidx, etype, ew, head, nxt, S, N);

    kg1<<<gblocks, 256, 0, stream>>>(S, wp2, h0b, gamma, beta, out, N, gblocks);
}

// Round 15
// 379.165 us; speedup vs baseline: 1.5401x; 1.0090x over previous
//
#include <hip/hip_runtime.h>
#include <hip/hip_bf16.h>

#define HID 256
#define LN_EPS 1e-5f
#define DENOM_EPS 1e-8f

typedef __attribute__((ext_vector_type(8))) short short8;
typedef __attribute__((ext_vector_type(4))) float f32x4;

#define WP1_ELEMS (28 * 256 * 32)   // K=896 packed, pre-scaled by 0.5
#define WP2_ELEMS (24 * 256 * 32)   // K=768 (3 rels x 256)

__device__ inline unsigned bfpk(float x, float y) {
    __hip_bfloat162 h = __float22bfloat162_rn(make_float2(x, y));
    return *reinterpret_cast<unsigned*>(&h);
}

__device__ inline void gld16(const void* g, void* l) {
    __builtin_amdgcn_global_load_lds(
        (const __attribute__((address_space(1))) void*)g,
        (__attribute__((address_space(3))) void*)l, 16, 0, 0);
}

__device__ inline f32x4 bf4_to_f32(uint2 p) {
    union { float f; unsigned u; } c;
    f32x4 r;
    c.u = (p.x & 0xFFFFu) << 16;  r[0] = c.f;
    c.u = (p.x & 0xFFFF0000u);    r[1] = c.f;
    c.u = (p.y & 0xFFFFu) << 16;  r[2] = c.f;
    c.u = (p.y & 0xFFFF0000u);    r[3] = c.f;
    return r;
}

// Pack weights: wp[ks32][col][kk] = W[ks32*32+kk][col] (*0.5 for wp1)
__global__ __launch_bounds__(256) void kpack(
    const float* __restrict__ wt, const float* __restrict__ wi,
    const float* __restrict__ wrel,
    __hip_bfloat16* __restrict__ wp1, __hip_bfloat16* __restrict__ wp2)
{
    int idx = blockIdx.x * 256 + threadIdx.x;
    if (idx < WP1_ELEMS) {
        int kk = idx & 31, col = (idx >> 5) & 255, ks = idx >> 13;
        int k = ks * 32 + kk;
        float v = (k < 384) ? wt[k * 256 + col] : wi[(k - 384) * 256 + col];
        wp1[idx] = __float2bfloat16(v * 0.5f);
    } else {
        int j = idx - WP1_ELEMS;
        if (j < WP2_ELEMS) {
            int kk = j & 31, col = (j >> 5) & 255, ks = j >> 13;
            int k = ks * 32 + kk;
            wp2[j] = __float2bfloat16(wrel[k * 256 + col]);
        }
    }
}

__global__ __launch_bounds__(256) void kchain(
    const int* __restrict__ edst, int* __restrict__ head, int* __restrict__ nxt, int E)
{
    int e = blockIdx.x * 256 + threadIdx.x;
    if (e < E) nxt[e] = atomicExch(&head[edst[e]], e);
}

// k2: 8 waves/block, one dst node per wave. Gathers BF16 h0 rows (512B/edge).
// S[d][rel*256+c] = bf16(acc[rel][c] / max(denom[rel], eps)), row-major [N][768].
__global__ __launch_bounds__(512) void k2_gather(
    const __hip_bfloat16* __restrict__ h0b, const int* __restrict__ esrc,
    const int* __restrict__ etype, const float* __restrict__ ew,
    const int* __restrict__ head, const int* __restrict__ nxt,
    __hip_bfloat16* __restrict__ S, int N)
{
    int w = threadIdx.x >> 6;
    int lane = threadIdx.x & 63;
    int d = blockIdx.x * 8 + w;
    if (d >= N) return;

    f32x4 a0 = {0.f, 0.f, 0.f, 0.f}, a1 = a0, a2 = a0;
    float d0 = 0.f, d1 = 0.f, d2 = 0.f;

    int e = head[d];
    while (e >= 0) {
        int src = esrc[e];
        int ty = etype[e];          // wave-uniform
        float we = ew[e];
        uint2 hv = *(const uint2*)(h0b + (size_t)src * HID + lane * 4);
        f32x4 h = bf4_to_f32(hv);
        if (ty == 0)      { a0 += we * h; d0 += we; }
        else if (ty == 1) { a1 += we * h; d1 += we; }
        else              { a2 += we * h; d2 += we; }
        e = nxt[e];
    }

    float i0 = 1.0f / fmaxf(d0, DENOM_EPS);
    float i1 = 1.0f / fmaxf(d1, DENOM_EPS);
    float i2 = 1.0f / fmaxf(d2, DENOM_EPS);
    __hip_bfloat16* row = S + (size_t)d * 768;
    uint2 p;
    p = make_uint2(bfpk(a0[0] * i0, a0[1] * i0), bfpk(a0[2] * i0, a0[3] * i0));
    *(uint2*)(row + 0   + lane * 4) = p;
    p = make_uint2(bfpk(a1[0] * i1, a1[1] * i1), bfpk(a1[2] * i1, a1[3] * i1));
    *(uint2*)(row + 256 + lane * 4) = p;
    p = make_uint2(bfpk(a2[0] * i2, a2[1] * i2), bfpk(a2[2] * i2, a2[3] * i2));
    *(uint2*)(row + 512 + lane * 4) = p;
}

// kg0: h0b = bf16(ft@wp1a + fi@wp1b) (0.5 pre-folded), row 0 zeroed.
// R8 structure verbatim (NO XCD swizzle): 64x256 tile, 4 waves, counted-vmcnt
// pair-unrolled loop, 3 LDS buffers, global_load_lds, both-sides swizzle.
__global__ __launch_bounds__(256, 4) void kg0(
    const float* __restrict__ ft, const float* __restrict__ fi,
    const __hip_bfloat16* __restrict__ wp,
    __hip_bfloat16* __restrict__ h0b, int N)
{
    constexpr int NSTEPS = 28;
    __shared__ __align__(16) unsigned char As[3][8192];

    const int t = threadIdx.x;
    const int lane = t & 63;
    const int w = t >> 6;
    const int m0 = blockIdx.x * 64;
    const int g = lane >> 4;
    const int rl = lane & 15;

    auto stageA = [&](int ks, int buf) {
#pragma unroll
        for (int j = 0; j < 2; ++j) {
            int slot = j * 4 + w;
            int r = slot * 8 + (lane >> 3);
            int grow = m0 + r; if (grow >= N) grow = m0;
            int q = (lane & 7) ^ (lane >> 3);
            const float* src = (ks < 12)
                ? (ft + (size_t)grow * 384 + ks * 32 + q * 4)
                : (fi + (size_t)grow * 512 + (ks - 12) * 32 + q * 4);
            gld16(src, As[buf] + slot * 1024);
        }
    };
    auto loadB = [&](short8 (&bf)[4], int ks) {
#pragma unroll
        for (int fc = 0; fc < 4; ++fc)
            bf[fc] = *(const short8*)((const short*)wp +
                      (size_t)(ks * 256 + w * 64 + fc * 16 + rl) * 32 + g * 8);
    };

    f32x4 acc[4][4];
#pragma unroll
    for (int i = 0; i < 4; ++i)
#pragma unroll
        for (int j = 0; j < 4; ++j) acc[i][j] = (f32x4){0.f, 0.f, 0.f, 0.f};

    auto compute = [&](int ks, short8 (&bf)[4]) {
        const unsigned char* Ab = As[ks % 3];
        short8 af[4];
#pragma unroll
        for (int fr = 0; fr < 4; ++fr) {
            int r = fr * 16 + rl;
            const unsigned char* base = Ab + r * 128;
            f32x4 lo = *(const f32x4*)(base + ((2 * g) ^ (r & 7)) * 16);
            f32x4 hi = *(const f32x4*)(base + ((2 * g + 1) ^ (r & 7)) * 16);
            union { short8 s8; unsigned u[4]; } cv;
            cv.u[0] = bfpk(lo[0], lo[1]);
            cv.u[1] = bfpk(lo[2], lo[3]);
            cv.u[2] = bfpk(hi[0], hi[1]);
            cv.u[3] = bfpk(hi[2], hi[3]);
            af[fr] = cv.s8;
        }
#pragma unroll
        for (int fr = 0; fr < 4; ++fr)
#pragma unroll
            for (int fc = 0; fc < 4; ++fc)
                acc[fr][fc] = __builtin_amdgcn_mfma_f32_16x16x32_bf16(af[fr], bf[fc], acc[fr][fc], 0, 0, 0);
    };

    short8 bfe[4], bfo[4];
    stageA(0, 0);
    stageA(1, 1);
    loadB(bfe, 0);

    constexpr int NP = NSTEPS / 2;
#pragma unroll 1
    for (int p = 0; p < NP; ++p) {
        const int ks = 2 * p;
        asm volatile("s_waitcnt vmcnt(6)" ::: "memory");
        __builtin_amdgcn_s_barrier();
        __builtin_amdgcn_sched_barrier(0);
        if (ks + 2 < NSTEPS) stageA(ks + 2, (ks + 2) % 3);
        loadB(bfo, ks + 1);
        compute(ks, bfe);
        if (p == NP - 1) asm volatile("s_waitcnt vmcnt(0)" ::: "memory");
        else             asm volatile("s_waitcnt vmcnt(6)" ::: "memory");
        __builtin_amdgcn_s_barrier();
        __builtin_amdgcn_sched_barrier(0);
        if (ks + 3 < NSTEPS) stageA(ks + 3, (ks + 3) % 3);
        if (ks + 2 < NSTEPS) loadB(bfe, ks + 2);
        compute(ks + 1, bfo);
    }

    const int cbase = w * 64;
#pragma unroll
    for (int fr = 0; fr < 4; ++fr)
#pragma unroll
        for (int reg = 0; reg < 4; ++reg) {
            int grow = m0 + fr * 16 + g * 4 + reg;
            if (grow >= N) continue;
#pragma unroll
            for (int fc = 0; fc < 4; ++fc) {
                float vv = acc[fr][fc][reg];
                if (grow == 0) vv = 0.f;
                h0b[(size_t)grow * 256 + cbase + fc * 16 + rl] = __float2bfloat16(vv);
            }
        }
}

// kg1: out = LN(h0b + S@wp2), row 0 zeroed. A = S bf16 [N][768], R8 structure
// (NO XCD swizzle).
__global__ __launch_bounds__(256, 4) void kg1(
    const __hip_bfloat16* __restrict__ Sb,
    const __hip_bfloat16* __restrict__ wp,
    const __hip_bfloat16* __restrict__ h0b,
    const float* __restrict__ gamma, const float* __restrict__ beta,
    float* __restrict__ out, int N)
{
    constexpr int NSTEPS = 24;
    __shared__ __align__(16) unsigned char As[3][4096];
    __shared__ float redS[64][4];
    __shared__ float redQ[64][4];

    const int t = threadIdx.x;
    const int lane = t & 63;
    const int w = t >> 6;
    const int m0 = blockIdx.x * 64;
    const int g = lane >> 4;
    const int rl = lane & 15;

    auto stageA = [&](int ks, int buf) {
        int r = w * 16 + (lane >> 2);
        int grow = m0 + r; if (grow >= N) grow = m0;
        int q = (lane & 3) ^ ((lane >> 3) & 3);
        const __hip_bfloat16* src = Sb + (size_t)grow * 768 + ks * 32 + q * 8;
        gld16(src, As[buf] + w * 1024);
    };
    auto loadB = [&](short8 (&bf)[4], int ks) {
#pragma unroll
        for (int fc = 0; fc < 4; ++fc)
            bf[fc] = *(const short8*)((const short*)wp +
                      (size_t)(ks * 256 + w * 64 + fc * 16 + rl) * 32 + g * 8);
    };

    f32x4 acc[4][4];
#pragma unroll
    for (int i = 0; i < 4; ++i)
#pragma unroll
        for (int j = 0; j < 4; ++j) acc[i][j] = (f32x4){0.f, 0.f, 0.f, 0.f};

    auto compute = [&](int ks, short8 (&bf)[4]) {
        const unsigned char* Ab = As[ks % 3];
        short8 af[4];
#pragma unroll
        for (int fr = 0; fr < 4; ++fr) {
            int r = fr * 16 + rl;
            af[fr] = *(const short8*)(Ab + r * 64 + (g ^ ((r >> 1) & 3)) * 16);
        }
#pragma unroll
        for (int fr = 0; fr < 4; ++fr)
#pragma unroll
            for (int fc = 0; fc < 4; ++fc)
                acc[fr][fc] = __builtin_amdgcn_mfma_f32_16x16x32_bf16(af[fr], bf[fc], acc[fr][fc], 0, 0, 0);
    };

    short8 bfe[4], bfo[4];
    stageA(0, 0);
    stageA(1, 1);
    loadB(bfe, 0);

    constexpr int NP = NSTEPS / 2;
#pragma unroll 1
    for (int p = 0; p < NP; ++p) {
        const int ks = 2 * p;
        asm volatile("s_waitcnt vmcnt(5)" ::: "memory");
        __builtin_amdgcn_s_barrier();
        __builtin_amdgcn_sched_barrier(0);
        if (ks + 2 < NSTEPS) stageA(ks + 2, (ks + 2) % 3);
        loadB(bfo, ks + 1);
        compute(ks, bfe);
        if (p == NP - 1) asm volatile("s_waitcnt vmcnt(0)" ::: "memory");
        else             asm volatile("s_waitcnt vmcnt(5)" ::: "memory");
        __builtin_amdgcn_s_barrier();
        __builtin_amdgcn_sched_barrier(0);
        if (ks + 3 < NSTEPS) stageA(ks + 3, (ks + 3) % 3);
        if (ks + 2 < NSTEPS) loadB(bfe, ks + 2);
        compute(ks + 1, bfo);
    }

    const int cbase = w * 64;
    // residual from bf16 h0
#pragma unroll
    for (int fr = 0; fr < 4; ++fr)
#pragma unroll
        for (int reg = 0; reg < 4; ++reg) {
            int grow = m0 + fr * 16 + g * 4 + reg;
            if (grow < N) {
#pragma unroll
                for (int fc = 0; fc < 4; ++fc)
                    acc[fr][fc][reg] +=
                        __bfloat162float(h0b[(size_t)grow * 256 + cbase + fc * 16 + rl]);
            }
        }
#pragma unroll
    for (int fr = 0; fr < 4; ++fr)
#pragma unroll
        for (int reg = 0; reg < 4; ++reg) {
            float s = 0.f, q = 0.f;
#pragma unroll
            for (int fc = 0; fc < 4; ++fc) {
                float vv = acc[fr][fc][reg];
                s += vv; q += vv * vv;
            }
#pragma unroll
            for (int off = 1; off < 16; off <<= 1) {
                s += __shfl_xor(s, off, 64);
                q += __shfl_xor(q, off, 64);
            }
            if (rl == 0) {
                int rli = fr * 16 + g * 4 + reg;
                redS[rli][w] = s;
                redQ[rli][w] = q;
            }
        }
    __syncthreads();
    float g4[4], b4[4];
#pragma unroll
    for (int fc = 0; fc < 4; ++fc) {
        g4[fc] = gamma[cbase + fc * 16 + rl];
        b4[fc] = beta[cbase + fc * 16 + rl];
    }
#pragma unroll
    for (int fr = 0; fr < 4; ++fr)
#pragma unroll
        for (int reg = 0; reg < 4; ++reg) {
            int rli = fr * 16 + g * 4 + reg;
            int grow = m0 + rli;
            if (grow >= N) continue;
            float s = redS[rli][0] + redS[rli][1] + redS[rli][2] + redS[rli][3];
            float q = redQ[rli][0] + redQ[rli][1] + redQ[rli][2] + redQ[rli][3];
            float mu  = s * (1.f / 256.f);
            float var = q * (1.f / 256.f) - mu * mu;
            float rstd = rsqrtf(var + LN_EPS);
#pragma unroll
            for (int fc = 0; fc < 4; ++fc) {
                float vv = (acc[fr][fc][reg] - mu) * rstd * g4[fc] + b4[fc];
                if (grow == 0) vv = 0.f;
                out[(size_t)grow * 256 + cbase + fc * 16 + rl] = vv;
            }
        }
}

extern "C" void kernel_launch(void* const* d_in, const int* in_sizes, int n_in,
                              void* d_out, int out_size, void* d_ws, size_t ws_size,
                              hipStream_t stream) {
    const int N = in_sizes[0] / 384;   // 100000
    const int E = in_sizes[7];         // 300000
    const float* ft    = (const float*)d_in[0];
    const float* fi    = (const float*)d_in[1];
    const float* wt    = (const float*)d_in[2];
    const float* wi    = (const float*)d_in[3];
    const float* wrel  = (const float*)d_in[4];
    const float* gamma = (const float*)d_in[5];
    const float* beta  = (const float*)d_in[6];
    const float* ew    = (const float*)d_in[7];
    const int*   eidx  = (const int*)d_in[8];
    const int*   etype = (const int*)d_in[9];
    float* out = (float*)d_out;

    // ws: S bf16 [N][768] | h0b bf16 [N][256] | head int[N] | nxt int[E] | wp1 | wp2
    __hip_bfloat16* S   = (__hip_bfloat16*)d_ws;
    __hip_bfloat16* h0b = S + (size_t)N * 768;
    int* head = (int*)(h0b + (size_t)N * 256);
    int* nxt  = head + N;
    __hip_bfloat16* wp1 = (__hip_bfloat16*)(nxt + E);
    __hip_bfloat16* wp2 = wp1 + WP1_ELEMS;

    hipMemsetAsync(head, 0xFF, (size_t)N * sizeof(int), stream);

    kpack<<<(WP1_ELEMS + WP2_ELEMS + 255) / 256, 256, 0, stream>>>(wt, wi, wrel, wp1, wp2);

    kchain<<<(E + 255) / 256, 256, 0, stream>>>(eidx + E, head, nxt, E);

    const int gblocks = (N + 63) / 64;                   // 1563
    kg0<<<gblocks, 256, 0, stream>>>(ft, fi, wp1, h0b, N);

    k2_gather<<<(N + 7) / 8, 512, 0, stream>>>(h0b, eidx, etype, ew, head, nxt, S, N);

    kg1<<<gblocks, 256, 0, stream>>>(S, wp2, h0b, gamma, beta, out, N);
}